// Round 20
// baseline (390.383 us; speedup 1.0000x reference)
//
#include <hip/hip_runtime.h>

typedef unsigned short u16;
typedef __attribute__((ext_vector_type(8))) short bf16x8;
typedef __attribute__((ext_vector_type(4))) float f32x4;

#define N_PIX 16384
static constexpr long NP = 4L * 128 * N_PIX;

__device__ __forceinline__ float bf2f(u16 h) {
  unsigned u = ((unsigned)h) << 16; float f; __builtin_memcpy(&f, &u, 4); return f;
}
__device__ __forceinline__ u16 f2bf(float f) {
  unsigned u; __builtin_memcpy(&u, &f, 4);
  u = (u + 0x7fffu + ((u >> 16) & 1u)) >> 16; return (u16)u;
}

__device__ __forceinline__ float blockReduceSum256(float v) {
  #pragma unroll
  for (int o = 32; o > 0; o >>= 1) v += __shfl_down(v, o, 64);
  __shared__ float sw[4];
  int lane = threadIdx.x & 63, w = threadIdx.x >> 6;
  if (lane == 0) sw[w] = v;
  __syncthreads();
  return (threadIdx.x == 0) ? (sw[0] + sw[1] + sw[2] + sw[3]) : 0.f;
}

// ---- 5 weight tensors f32 -> bf16 ----
__global__ __launch_bounds__(256) void wconv5_k(const float* __restrict__ a0, u16* __restrict__ o0, long n0,
                                                const float* __restrict__ a1, u16* __restrict__ o1, long n1,
                                                const float* __restrict__ a2, u16* __restrict__ o2, long n2,
                                                const float* __restrict__ a3, u16* __restrict__ o3, long n3,
                                                const float* __restrict__ a4, u16* __restrict__ o4, long n4) {
  long i = (long)blockIdx.x * 256 + threadIdx.x;
  if (i < n0) o0[i] = f2bf(a0[i]);
  if (i < n1) o1[i] = f2bf(a1[i]);
  if (i < n2) o2[i] = f2bf(a2[i]);
  if (i < n3) o3[i] = f2bf(a3[i]);
  if (i < n4) o4[i] = f2bf(a4[i]);
}

// ---- squeeze: mean over HW of concat -> [4,256] f32 ; emit bf16 concat ----
__global__ __launch_bounds__(256) void squeeze_k(const float* __restrict__ vi,
                                                 const float* __restrict__ ir,
                                                 float* __restrict__ sq,
                                                 u16* __restrict__ cbf) {
  int c = blockIdx.x, b = blockIdx.y, tid = threadIdx.x;
  const float* src = (c < 128) ? (vi + ((long)b * 128 + c) * N_PIX)
                               : (ir + ((long)b * 128 + (c - 128)) * N_PIX);
  const f32x4* src4 = (const f32x4*)src;
  u16* dst = cbf + ((long)b * 256 + c) * N_PIX;
  float s = 0.f;
  #pragma unroll
  for (int j = 0; j < 8; ++j) {
    f32x4 v0 = src4[j * 512 + tid * 2];
    f32x4 v1 = src4[j * 512 + tid * 2 + 1];
    s += v0.x + v0.y + v0.z + v0.w + v1.x + v1.y + v1.z + v1.w;
    bf16x8 r;
    r[0] = (short)f2bf(v0.x); r[1] = (short)f2bf(v0.y);
    r[2] = (short)f2bf(v0.z); r[3] = (short)f2bf(v0.w);
    r[4] = (short)f2bf(v1.x); r[5] = (short)f2bf(v1.y);
    r[6] = (short)f2bf(v1.z); r[7] = (short)f2bf(v1.w);
    *(bf16x8*)(dst + j * 2048 + tid * 8) = r;
  }
  float t = blockReduceSum256(s);
  if (tid == 0) sq[b * 256 + c] = t * (1.f / 16384.f);
}

// ---- merged: SE MLP + top128 rank (x==64) | text MLP layer1 (x<64) ----
__global__ __launch_bounds__(256) void se_text1_k(const float* __restrict__ sq,
                                                  const float* __restrict__ sew1,
                                                  const float* __restrict__ sew2,
                                                  int* __restrict__ idx,
                                                  const float* __restrict__ tc,
                                                  const float* __restrict__ tw1,
                                                  const float* __restrict__ tb1,
                                                  float* __restrict__ t1f) {
  int b = blockIdx.y, tid = threadIdx.x;
  __shared__ float sm[544];
  if (blockIdx.x == 64) {
    float* s_sq = sm; float* s_h1 = sm + 256; float* s_cw = sm + 288;
    s_sq[tid] = sq[b * 256 + tid];
    __syncthreads();
    if (tid < 32) {
      float s = 0.f;
      for (int c = 0; c < 256; ++c) s += s_sq[c] * sew1[tid * 256 + c];
      s_h1[tid] = fmaxf(s, 0.f);
    }
    __syncthreads();
    {
      float s = 0.f;
      #pragma unroll
      for (int j = 0; j < 32; ++j) s += s_h1[j] * sew2[tid * 32 + j];
      s_cw[tid] = 1.f / (1.f + expf(-s));
    }
    __syncthreads();
    float my = s_cw[tid];
    int rk = 0;
    for (int c = 0; c < 256; ++c) {
      float o = s_cw[c];
      rk += (o > my) || (o == my && c < tid);
    }
    if (rk < 128) idx[b * 128 + rk] = tid;
  } else {
    float* s_tc = sm;
    int j0 = blockIdx.x * 8;
    s_tc[tid] = tc[b * 512 + tid];
    s_tc[tid + 256] = tc[b * 512 + 256 + tid];
    __syncthreads();
    int w = tid >> 6, lane = tid & 63;
    #pragma unroll
    for (int r = 0; r < 2; ++r) {
      int j = j0 + w * 2 + r;
      const float* wr = tw1 + (long)j * 512;
      float s = 0.f;
      #pragma unroll
      for (int k = 0; k < 8; ++k) s += s_tc[lane + k * 64] * wr[lane + k * 64];
      #pragma unroll
      for (int o = 32; o > 0; o >>= 1) s += __shfl_down(s, o, 64);
      if (lane == 0) t1f[b * 512 + j] = fmaxf(s + tb1[j], 0.f);
    }
  }
}

// ---- text MLP layer2 ----
__global__ __launch_bounds__(256) void text2_k(const float* __restrict__ t1f,
                                               const float* __restrict__ tw2,
                                               const float* __restrict__ tb2,
                                               float* __restrict__ tf) {
  int b = blockIdx.y, j0 = blockIdx.x * 8, tid = threadIdx.x;
  __shared__ float s_t1[512];
  s_t1[tid] = t1f[b * 512 + tid];
  s_t1[tid + 256] = t1f[b * 512 + 256 + tid];
  __syncthreads();
  int w = tid >> 6, lane = tid & 63;
  #pragma unroll
  for (int r = 0; r < 2; ++r) {
    int j = j0 + w * 2 + r;
    const float* wr = tw2 + (long)j * 512;
    float s = 0.f;
    #pragma unroll
    for (int k = 0; k < 8; ++k) s += s_t1[lane + k * 64] * wr[lane + k * 64];
    #pragma unroll
    for (int o = 32; o > 0; o >>= 1) s += __shfl_down(s, o, 64);
    if (lane == 0) tf[b * 256 + j] = s + tb2[j];
  }
}

// ---- argsort-rank of tf -> sidx ----
__global__ __launch_bounds__(256) void rank2_k(const float* __restrict__ tf,
                                               int* __restrict__ sidx) {
  int b = blockIdx.x, tid = threadIdx.x;
  __shared__ float s_tf[256];
  s_tf[tid] = tf[b * 256 + tid];
  __syncthreads();
  float my = s_tf[tid];
  int rk = 0;
  for (int c = 0; c < 256; ++c) {
    float o = s_tf[c];
    rk += (o > my) || (o == my && c < tid);
  }
  sidx[b * 256 + rk] = tid;
}

// ---- fold conv1x1+shuffle+conv_out+select into hi/lo bf16 M_b[128,256] ----
__global__ __launch_bounds__(128) void mcomb_k(const float* __restrict__ w2,
                                               const float* __restrict__ w2b,
                                               const float* __restrict__ w1,
                                               const float* __restrict__ w1b,
                                               const int* __restrict__ idx,
                                               const int* __restrict__ sidx,
                                               u16* __restrict__ mch,
                                               u16* __restrict__ mcl,
                                               float* __restrict__ bcomb) {
  int o = blockIdx.x, b = blockIdx.y, tid = threadIdx.x;
  __shared__ float s_w2[256];
  __shared__ int s_sx[256];
  s_w2[tid] = w2[o * 256 + tid];
  s_w2[tid + 128] = w2[o * 256 + tid + 128];
  s_sx[tid] = sidx[b * 256 + tid] & 255;
  s_sx[tid + 128] = sidx[b * 256 + tid + 128] & 255;
  u16* hrow = mch + ((long)b * 128 + o) * 256;
  u16* lrow = mcl + ((long)b * 128 + o) * 256;
  hrow[tid] = 0; hrow[tid + 128] = 0;
  lrow[tid] = 0; lrow[tid + 128] = 0;
  __syncthreads();
  float s = 0.f;
  for (int j = 0; j < 256; ++j) s += s_w2[j] * w1[s_sx[j] * 128 + tid];
  int cc = idx[b * 128 + tid] & 255;
  u16 hi = f2bf(s);
  hrow[cc] = hi;
  lrow[cc] = f2bf(s - bf2f(hi));
  if (tid == 0) {
    float bb = w2b[o];
    for (int j = 0; j < 256; ++j) bb += s_w2[j] * w1b[s_sx[j]];
    bcomb[b * 128 + o] = bb;
  }
}

// ---- fused dual GEMM: BK=64; outputs out1 f32 spatial + qinT/img2T transposed bf16 ----
__global__ __launch_bounds__(256) void gemm_dual_k(
    const u16* __restrict__ W2b, const float* __restrict__ b2,
    const u16* __restrict__ Mch, const u16* __restrict__ Mcl,
    const float* __restrict__ bc, const u16* __restrict__ Xb,
    float* __restrict__ out1, u16* __restrict__ qinT, u16* __restrict__ img2T) {
  const int N = N_PIX;
  int n0 = blockIdx.x * 64, o0 = blockIdx.y * 64, bz = blockIdx.z, tid = threadIdx.x;
  __shared__ __align__(16) char smem[36864];
  u16* A1  = (u16*)smem;            // [64][72]
  u16* A2h = (u16*)(smem + 9216);
  u16* A2l = (u16*)(smem + 18432);
  u16* Xs  = (u16*)(smem + 27648);
  f32x4 acc1[4], acc2[4];
  #pragma unroll
  for (int i = 0; i < 4; ++i) { acc1[i] = (f32x4){0,0,0,0}; acc2[i] = (f32x4){0,0,0,0}; }
  int wv = tid >> 6, lane = tid & 63;
  int lr = lane & 15, lkq = (lane >> 4) * 8;
  for (int kt = 0; kt < 4; ++kt) {
    int k0 = kt << 6;
    {
      int r = tid >> 2, o = o0 + r;
      #pragma unroll
      for (int cc = 0; cc < 2; ++cc) {
        int col = ((tid & 3) << 3) + cc * 32;
        int k = k0 + col;
        *(bf16x8*)&A1[r * 72 + col] = *(const bf16x8*)(W2b + (long)o * 256 + k);
        *(bf16x8*)&A2h[r * 72 + col] = *(const bf16x8*)(Mch + ((long)bz * 128 + o) * 256 + k);
        *(bf16x8*)&A2l[r * 72 + col] = *(const bf16x8*)(Mcl + ((long)bz * 128 + o) * 256 + k);
      }
    }
    {
      int n = tid & 63;
      const u16* src = Xb + (long)bz * 256 * N + n0 + n;
      #pragma unroll
      for (int cc = 0; cc < 2; ++cc) {
        int kb = ((tid >> 6) << 3) + cc * 32;
        int k = k0 + kb;
        bf16x8 t;
        #pragma unroll
        for (int i = 0; i < 8; ++i) t[i] = (short)src[(long)(k + i) * N];
        *(bf16x8*)&Xs[n * 72 + kb] = t;
      }
    }
    __syncthreads();
    #pragma unroll
    for (int kk = 0; kk < 2; ++kk) {
      int lk = kk * 32 + lkq;
      bf16x8 a1 = *(const bf16x8*)&A1[(wv * 16 + lr) * 72 + lk];
      bf16x8 a2h = *(const bf16x8*)&A2h[(wv * 16 + lr) * 72 + lk];
      bf16x8 a2l = *(const bf16x8*)&A2l[(wv * 16 + lr) * 72 + lk];
      #pragma unroll
      for (int nt = 0; nt < 4; ++nt) {
        bf16x8 bfr = *(const bf16x8*)&Xs[(nt * 16 + lr) * 72 + lk];
        acc1[nt] = __builtin_amdgcn_mfma_f32_16x16x32_bf16(a1, bfr, acc1[nt], 0, 0, 0);
        acc2[nt] = __builtin_amdgcn_mfma_f32_16x16x32_bf16(a2h, bfr, acc2[nt], 0, 0, 0);
        acc2[nt] = __builtin_amdgcn_mfma_f32_16x16x32_bf16(a2l, bfr, acc2[nt], 0, 0, 0);
      }
    }
    __syncthreads();
  }
  // ---- staged epilogue: st1 f32 spatial [o][n]; stq/sti u16 transposed [n][o] ----
  float* st1 = (float*)smem;               // 64*68*4 = 17408B
  u16*  stq = (u16*)(smem + 17408);        // 64*68*2 = 8704B
  u16*  sti = (u16*)(smem + 26112);        // 8704B
  #pragma unroll
  for (int nt = 0; nt < 4; ++nt)
    #pragma unroll
    for (int r4 = 0; r4 < 4; ++r4) {
      int o_l = wv * 16 + (lane >> 4) * 4 + r4;
      int n_l = nt * 16 + (lane & 15);
      float v1 = acc1[nt][r4] + b2[o0 + o_l];
      float v2 = acc2[nt][r4] + bc[bz * 128 + o0 + o_l];
      st1[o_l * 68 + n_l] = v1;
      stq[n_l * 68 + o_l] = f2bf(v2);
      sti[n_l * 68 + o_l] = f2bf(v1);
    }
  __syncthreads();
  {
    int row = tid >> 2, colb = (tid & 3) * 16;
    // out1 f32 spatial: 64B/thread
    float* dst = out1 + ((long)bz * 128 + o0 + row) * N + n0 + colb;
    #pragma unroll
    for (int j = 0; j < 4; ++j)
      *(f32x4*)(dst + j * 4) = *(f32x4*)&st1[row * 68 + colb + j * 4];
    // qinT / img2T transposed: 32B/thread each
    u16* dq = qinT + ((long)bz * N_PIX + n0 + row) * 128 + o0 + colb;
    u16* di = img2T + ((long)bz * N_PIX + n0 + row) * 128 + o0 + colb;
    *(bf16x8*)dq = *(bf16x8*)&stq[row * 68 + colb];
    *(bf16x8*)(dq + 8) = *(bf16x8*)&stq[row * 68 + colb + 8];
    *(bf16x8*)di = *(bf16x8*)&sti[row * 68 + colb];
    *(bf16x8*)(di + 8) = *(bf16x8*)&sti[row * 68 + colb + 8];
  }
}

// ---- rowwise LayerNorm on transposed [b][N][128] tensors, in-place; y=0:t0, y=1:t1 ----
__global__ __launch_bounds__(256) void lnrow_k(u16* __restrict__ t0, u16* __restrict__ t1,
                                               const float* __restrict__ g1, const float* __restrict__ b1,
                                               const float* __restrict__ g2, const float* __restrict__ b2) {
  int y = blockIdx.y, tid = threadIdx.x;
  u16* buf = y ? t1 : t0;
  const float* g = y ? g2 : g1;
  const float* bb = y ? b2 : b1;
  __shared__ float gs[128], bs[128];
  if (tid < 128) { gs[tid] = g[tid]; bs[tid] = bb[tid]; }
  __syncthreads();
  long p = (long)blockIdx.x * 256 + tid;   // 65536 pixels per tensor
  u16* src = buf + p * 128;
  bf16x8 v[16];
  float sum = 0.f, sq = 0.f;
  #pragma unroll
  for (int j = 0; j < 16; ++j) {
    v[j] = *(const bf16x8*)(src + j * 8);
    #pragma unroll
    for (int i = 0; i < 8; ++i) { float f = bf2f((u16)v[j][i]); sum += f; sq += f * f; }
  }
  float mu = sum * (1.f / 128.f);
  float var = sq * (1.f / 128.f) - mu * mu;
  float rs = rsqrtf(fmaxf(var, 0.f) + 1e-5f);
  #pragma unroll
  for (int j = 0; j < 16; ++j) {
    bf16x8 r;
    #pragma unroll
    for (int i = 0; i < 8; ++i) {
      float f = bf2f((u16)v[j][i]);
      r[i] = (short)f2bf((f - mu) * rs * gs[j * 8 + i] + bs[j * 8 + i]);
    }
    *(bf16x8*)(src + j * 8) = r;
  }
}

// ---------------- generic MFMA GEMM, OT o-tiles of 64 rows, coalesced epilogue ----------------
// AMODE: 2=bf16 W, 3=per-batch bf16 hi/lo.
// XT: 0=spatial X via LDS k-gather; 3=transposed X via LDS + DIRECT A (K==128)
template<int AMODE, int RESADD, int OUTF, int XT, int OT>
__global__ __launch_bounds__(256) void gemm_k(
    const u16* __restrict__ Ah, const u16* __restrict__ Alo, long a_bstride,
    const u16* __restrict__ X, long x_bstride,
    const u16* __restrict__ res, long res_bstride,
    void* __restrict__ outv, long out_bstride,
    int O, int K) {
  const int N = N_PIX;
  int n0 = blockIdx.x * 64;
  int o0 = blockIdx.y * 64 * OT;
  int bz = blockIdx.z;
  int tid = threadIdx.x;
  int wv = tid >> 6, lane = tid & 63;
  int lr = lane & 15, lkq = (lane >> 4) * 8;
  __shared__ __align__(16) u16 Xs[64][136];
  __shared__ __align__(16) u16 As[(XT == 3) ? 1 : 64][136];
  __shared__ __align__(16) u16 Al[(AMODE == 3) ? 64 : 1][136];
  f32x4 acc[OT][4];
  #pragma unroll
  for (int ot = 0; ot < OT; ++ot)
    #pragma unroll
    for (int i = 0; i < 4; ++i) acc[ot][i] = (f32x4){0.f, 0.f, 0.f, 0.f};

  if (XT == 3) {
    {
      int n = tid >> 2, koff = (tid & 3) << 5;
      const u16* src = X + (long)bz * x_bstride + (long)(n0 + n) * 128 + koff;
      #pragma unroll
      for (int j = 0; j < 4; ++j)
        *(bf16x8*)&Xs[n][koff + j * 8] = *(const bf16x8*)(src + j * 8);
    }
    __syncthreads();
    #pragma unroll
    for (int ot = 0; ot < OT; ++ot) {
      int oc = o0 + ot * 64 + wv * 16 + lr;
      if (oc > O - 1) oc = O - 1;
      const u16* Arow = Ah + (long)oc * 128;
      bf16x8 afr[4];
      #pragma unroll
      for (int kk = 0; kk < 4; ++kk) afr[kk] = *(const bf16x8*)(Arow + kk * 32 + lkq);
      #pragma unroll
      for (int kk = 0; kk < 4; ++kk) {
        int lk = kk * 32 + lkq;
        #pragma unroll
        for (int nt = 0; nt < 4; ++nt) {
          bf16x8 bfr = *(const bf16x8*)&Xs[nt * 16 + lr][lk];
          acc[ot][nt] = __builtin_amdgcn_mfma_f32_16x16x32_bf16(afr[kk], bfr, acc[ot][nt], 0, 0, 0);
        }
      }
    }
    __syncthreads();
  } else {
    int nk = (K + 127) >> 7;
    for (int kt = 0; kt < nk; ++kt) {
      int k0 = kt << 7;
      {
        int n = tid & 63;
        const u16* src = X + (long)bz * x_bstride + n0 + n;
        #pragma unroll
        for (int cc = 0; cc < 4; ++cc) {
          int kb = ((tid >> 6) << 3) + cc * 32;
          int k = k0 + kb;
          bf16x8 t;
          #pragma unroll
          for (int i = 0; i < 8; ++i)
            t[i] = (short)((k + i < K) ? src[(long)(k + i) * N] : (u16)0);
          *(bf16x8*)&Xs[n][kb] = t;
        }
      }
      #pragma unroll
      for (int ot = 0; ot < OT; ++ot) {
        {
          int r = tid >> 2, o = o0 + ot * 64 + r;
          #pragma unroll
          for (int cc = 0; cc < 4; ++cc) {
            int col = ((tid & 3) << 3) + cc * 32;
            int k = k0 + col;
            if (AMODE == 2) {
              bf16x8 t;
              if (o < O && k + 8 <= K) {
                t = *(const bf16x8*)(Ah + (long)o * K + k);
              } else {
                #pragma unroll
                for (int i = 0; i < 8; ++i)
                  t[i] = (short)((o < O && k + i < K) ? Ah[(long)o * K + k + i] : (u16)0);
              }
              *(bf16x8*)&As[r][col] = t;
            } else {
              long base = (long)bz * a_bstride + (long)o * K + k;
              *(bf16x8*)&As[r][col] = *(const bf16x8*)(Ah + base);
              *(bf16x8*)&Al[r][col] = *(const bf16x8*)(Alo + base);
            }
          }
        }
        __syncthreads();
        #pragma unroll
        for (int kk = 0; kk < 4; ++kk) {
          int lk = kk * 32 + lkq;
          bf16x8 afr = *(const bf16x8*)&As[wv * 16 + lr][lk];
          bf16x8 alr;
          if (AMODE == 3) alr = *(const bf16x8*)&Al[wv * 16 + lr][lk];
          #pragma unroll
          for (int nt = 0; nt < 4; ++nt) {
            bf16x8 bfr = *(const bf16x8*)&Xs[nt * 16 + lr][lk];
            acc[ot][nt] = __builtin_amdgcn_mfma_f32_16x16x32_bf16(afr, bfr, acc[ot][nt], 0, 0, 0);
            if (AMODE == 3)
              acc[ot][nt] = __builtin_amdgcn_mfma_f32_16x16x32_bf16(alr, bfr, acc[ot][nt], 0, 0, 0);
          }
        }
        __syncthreads();
      }
    }
  }

  // ---- coalesced epilogue per o-tile ----
  #pragma unroll
  for (int ot = 0; ot < OT; ++ot) {
    if (ot > 0) __syncthreads();
    if (OUTF == 0) {
      u16* st = &Xs[0][0];
      #pragma unroll
      for (int nt = 0; nt < 4; ++nt)
        #pragma unroll
        for (int r4 = 0; r4 < 4; ++r4) {
          int row = wv * 16 + (lane >> 4) * 4 + r4;
          int col = nt * 16 + (lane & 15);
          st[row * 68 + col] = f2bf(acc[ot][nt][r4]);
        }
      __syncthreads();
      #pragma unroll
      for (int it = 0; it < 2; ++it) {
        int row = (tid >> 3) + it * 32;
        int col = (tid & 7) * 8;
        int o = o0 + ot * 64 + row;
        if (o < O) {
          bf16x8 v = *(bf16x8*)&st[row * 68 + col];
          *(bf16x8*)((u16*)outv + (long)bz * out_bstride + (long)o * N + n0 + col) = v;
        }
      }
    } else {
      float* st = (float*)&Xs[0][0];
      #pragma unroll
      for (int nt = 0; nt < 4; ++nt)
        #pragma unroll
        for (int r4 = 0; r4 < 4; ++r4) {
          int row = wv * 16 + (lane >> 4) * 4 + r4;
          int col = nt * 16 + (lane & 15);
          st[row * 68 + col] = acc[ot][nt][r4];
        }
      __syncthreads();
      {
        int row = tid >> 2, colb = (tid & 3) * 16;
        int o = o0 + ot * 64 + row;
        if (o < O) {
          float* dst = (float*)outv + (long)bz * out_bstride + (long)o * N + n0 + colb;
          bf16x8 rv0, rv1;
          if (RESADD) {
            const u16* rp = res + (long)bz * res_bstride + (long)o * N + n0 + colb;
            rv0 = *(const bf16x8*)rp;
            rv1 = *(const bf16x8*)(rp + 8);
          }
          #pragma unroll
          for (int j = 0; j < 4; ++j) {
            f32x4 v = *(f32x4*)&st[row * 68 + colb + j * 4];
            if (RESADD) {
              #pragma unroll
              for (int i = 0; i < 4; ++i) {
                int idx = j * 4 + i;
                u16 rr = (u16)((idx < 8) ? rv0[idx] : rv1[idx - 8]);
                v[i] += bf2f(rr);
              }
            }
            *(f32x4*)(dst + j * 4) = v;
          }
        }
      }
    }
  }
}

// ---- LN3: bf16 spatial in, TRANSPOSED bf16 out ----
__global__ __launch_bounds__(256) void lnt_k(const u16* __restrict__ in,
                                             const float* __restrict__ gamma,
                                             const float* __restrict__ beta,
                                             u16* __restrict__ outT) {
  int p0 = blockIdx.x * 64, b = blockIdx.y, tid = threadIdx.x;
  int px = tid & 63, g4 = tid >> 6;
  __shared__ float tile[128][65];
  __shared__ float red[8][64];
  __shared__ float gmm[128], bta[128], mu_s[64], rs_s[64];
  if (tid < 128) { gmm[tid] = gamma[tid]; bta[tid] = beta[tid]; }
  long bofs = (long)b * 128 * N_PIX;
  float s = 0.f;
  for (int c = g4; c < 128; c += 4) {
    float v = bf2f(in[bofs + (long)c * N_PIX + p0 + px]);
    tile[c][px] = v;
    s += v;
  }
  red[g4][px] = s;
  __syncthreads();
  if (g4 == 0) mu_s[px] = (red[0][px] + red[1][px] + red[2][px] + red[3][px]) * (1.f / 128.f);
  __syncthreads();
  float mu = mu_s[px];
  float s2 = 0.f;
  for (int c = g4; c < 128; c += 4) { float d = tile[c][px] - mu; s2 += d * d; }
  red[4 + g4][px] = s2;
  __syncthreads();
  if (g4 == 0) {
    float var = (red[4][px] + red[5][px] + red[6][px] + red[7][px]) * (1.f / 128.f);
    rs_s[px] = rsqrtf(var + 1e-5f);
  }
  __syncthreads();
  float rs = rs_s[px];
  for (int c = g4; c < 128; c += 4)
    tile[c][px] = (tile[c][px] - mu) * rs * gmm[c] + bta[c];
  __syncthreads();
  int px2 = tid >> 2, c0 = (tid & 3) << 5;
  u16* dst = outT + ((long)b * N_PIX + p0 + px2) * 128 + c0;
  #pragma unroll
  for (int j = 0; j < 4; ++j) {
    bf16x8 r;
    #pragma unroll
    for (int i = 0; i < 8; ++i) r[i] = (short)f2bf(tile[c0 + j * 8 + i][px2]);
    *(bf16x8*)(dst + j * 8) = r;
  }
}

// ---- merged LDS-tiled depthwise 3x3: planes 0..511 = Q, 512..1535 = KV ----
__global__ __launch_bounds__(256) void dw3t2_k(const u16* __restrict__ inQ,
                                               const float* __restrict__ wQ,
                                               u16* __restrict__ outQ,
                                               const u16* __restrict__ inKV,
                                               const float* __restrict__ wKV,
                                               u16* __restrict__ outKV) {
  int gp = blockIdx.x >> 3, stripe = blockIdx.x & 7, tid = threadIdx.x;
  const u16* in; const float* w; u16* out; int c; long pbase;
  if (gp < 512) { in = inQ;  w = wQ;  out = outQ;  c = gp & 127;  pbase = (long)gp * N_PIX; }
  else { int p2 = gp - 512; in = inKV; w = wKV; out = outKV; c = p2 & 255; pbase = (long)p2 * N_PIX; }
  int y0 = stripe * 16;
  __shared__ __align__(16) u16 tile[18][136];
  for (int v = tid; v < 288; v += 256) {
    int r = v >> 4, col = (v & 15) << 3;
    int y = y0 - 1 + r;
    bf16x8 t;
    #pragma unroll
    for (int i = 0; i < 8; ++i) t[i] = 0;
    if (y >= 0 && y < 128) t = *(const bf16x8*)(in + pbase + y * 128 + col);
    *(bf16x8*)&tile[r][col] = t;
  }
  float wv[9];
  #pragma unroll
  for (int j = 0; j < 9; ++j) wv[j] = w[c * 9 + j];
  __syncthreads();
  int row = tid >> 4, col0 = (tid & 15) << 3;
  float a[3][10];
  #pragma unroll
  for (int dr = 0; dr < 3; ++dr)
    #pragma unroll
    for (int i = 0; i < 10; ++i) {
      int x = col0 - 1 + i;
      a[dr][i] = (x >= 0 && x < 128) ? bf2f(tile[row + dr][x]) : 0.f;
    }
  bf16x8 res;
  #pragma unroll
  for (int j = 0; j < 8; ++j) {
    float s = 0.f;
    #pragma unroll
    for (int dr = 0; dr < 3; ++dr)
      #pragma unroll
      for (int dx = 0; dx < 3; ++dx) s += wv[dr * 3 + dx] * a[dr][j + dx];
    res[j] = (short)f2bf(s);
  }
  *(bf16x8*)(out + pbase + (y0 + row) * 128 + col0) = res;
}

// ---- batched LDS-tiled FFN tail ----
__global__ __launch_bounds__(256) void dw3gelu4_k(const u16* __restrict__ ft,
                                                  const float* __restrict__ w,
                                                  u16* __restrict__ fg) {
  int plane = blockIdx.x >> 3, stripe = blockIdx.x & 7, tid = threadIdx.x;
  int b = plane / 340, c = plane % 340;
  const u16* t1 = ft + ((long)b * 680 + c) * N_PIX;
  const u16* t2 = ft + ((long)b * 680 + 340 + c) * N_PIX;
  u16* g = fg + ((long)b * 340 + c) * N_PIX;
  int y0 = stripe * 16;
  __shared__ __align__(16) u16 ta[18][136];
  __shared__ __align__(16) u16 tb[18][136];
  for (int v = tid; v < 288; v += 256) {
    int r = v >> 4, col = (v & 15) << 3;
    int y = y0 - 1 + r;
    bf16x8 u1, u2;
    #pragma unroll
    for (int i = 0; i < 8; ++i) { u1[i] = 0; u2[i] = 0; }
    if (y >= 0 && y < 128) {
      u1 = *(const bf16x8*)(t1 + y * 128 + col);
      u2 = *(const bf16x8*)(t2 + y * 128 + col);
    }
    *(bf16x8*)&ta[r][col] = u1;
    *(bf16x8*)&tb[r][col] = u2;
  }
  float w1[9], w2[9];
  #pragma unroll
  for (int j = 0; j < 9; ++j) { w1[j] = w[c * 9 + j]; w2[j] = w[(340 + c) * 9 + j]; }
  __syncthreads();
  int row = tid >> 4, col0 = (tid & 15) << 3;
  float a[3][10], bb[3][10];
  #pragma unroll
  for (int dr = 0; dr < 3; ++dr)
    #pragma unroll
    for (int i = 0; i < 10; ++i) {
      int x = col0 - 1 + i;
      bool ok = (x >= 0 && x < 128);
      a[dr][i] = ok ? bf2f(ta[row + dr][x]) : 0.f;
      bb[dr][i] = ok ? bf2f(tb[row + dr][x]) : 0.f;
    }
  bf16x8 res;
  #pragma unroll
  for (int j = 0; j < 8; ++j) {
    float s1 = 0.f, s2 = 0.f;
    #pragma unroll
    for (int dr = 0; dr < 3; ++dr)
      #pragma unroll
      for (int dx = 0; dx < 3; ++dx) {
        s1 += w1[dr * 3 + dx] * a[dr][j + dx];
        s2 += w2[dr * 3 + dx] * bb[dr][j + dx];
      }
    float gl = 0.5f * s1 * (1.f + erff(s1 * 0.70710678118f));
    res[j] = (short)f2bf(gl * s2);
  }
  *(bf16x8*)(g + (y0 + row) * 128 + col0) = res;
}

// ---- merged row L2 norms ----
__global__ __launch_bounds__(256) void rownorm2_k(const u16* __restrict__ q,
                                                  const u16* __restrict__ kv,
                                                  float* __restrict__ qn,
                                                  float* __restrict__ kn) {
  int x = blockIdx.x, b = blockIdx.y, tid = threadIdx.x;
  const u16* src;
  float* dst;
  if (x < 128) { src = q + (long)b * 128 * N_PIX + (long)x * N_PIX; dst = qn + b * 128 + x; }
  else { int r = x - 128; src = kv + (long)b * 256 * N_PIX + (long)r * N_PIX; dst = kn + b * 128 + r; }
  float s = 0.f;
  #pragma unroll
  for (int j = 0; j < 8; ++j) {
    bf16x8 v = *(const bf16x8*)(src + j * 2048 + tid * 8);
    #pragma unroll
    for (int i = 0; i < 8; ++i) { float f = bf2f((u16)v[i]); s += f * f; }
  }
  float t = blockReduceSum256(s);
  if (tid == 0) *dst = sqrtf(t);
}

// ---- attn partials ----
__global__ __launch_bounds__(256) void attn_part_k(const u16* __restrict__ q,
                                                   const u16* __restrict__ kbase,
                                                   long kbstride,
                                                   float* __restrict__ part) {
  int ch = blockIdx.x, h = blockIdx.y, b = blockIdx.z, tid = threadIdx.x;
  int n0 = ch * 256;
  __shared__ __align__(16) u16 qc[16][280];
  __shared__ __align__(16) u16 kc[16][280];
  #pragma unroll
  for (int j = 0; j < 2; ++j) {
    int v = tid + j * 256;
    int r = v >> 5, col = (v & 31) << 3;
    *(bf16x8*)&qc[r][col] = *(const bf16x8*)(q + ((long)b * 128 + h * 16 + r) * N_PIX + n0 + col);
    *(bf16x8*)&kc[r][col] = *(const bf16x8*)(kbase + (long)b * kbstride + (long)(h * 16 + r) * N_PIX + n0 + col);
  }
  __syncthreads();
  int c = tid >> 4, d = tid & 15;
  float acc = 0.f;
  #pragma unroll 4
  for (int nb = 0; nb < 32; ++nb) {
    bf16x8 qv = *(const bf16x8*)&qc[c][nb * 8];
    bf16x8 kv = *(const bf16x8*)&kc[d][nb * 8];
    #pragma unroll
    for (int i = 0; i < 8; ++i) acc += bf2f((u16)qv[i]) * bf2f((u16)kv[i]);
  }
  part[(long)((((b * 8 + h) * 16 + c) * 16 + d)) * 64 + ch] = acc;
}

// ---- reduce partials + cosine scaling ----
__global__ __launch_bounds__(256) void attn_reduce_k(const float* __restrict__ part,
                                                     const float* __restrict__ qn,
                                                     const float* __restrict__ kn,
                                                     const float* __restrict__ temp,
                                                     float* __restrict__ attnm) {
  int idx = blockIdx.x * 256 + threadIdx.x;
  const float* p = part + (long)idx * 64;
  float s = 0.f;
  #pragma unroll
  for (int j = 0; j < 64; ++j) s += p[j];
  int d = idx & 15, c = (idx >> 4) & 15, h = (idx >> 8) & 7, b = idx >> 11;
  float nq = fmaxf(qn[b * 128 + h * 16 + c], 1e-12f);
  float nk = fmaxf(kn[b * 128 + h * 16 + d], 1e-12f);
  attnm[idx] = s / (nq * nk) * temp[h];
}

// ---- top14 threshold + softmax + fold proj into hi/lo Cmb ----
__global__ __launch_bounds__(128) void score_cmb_k(const float* __restrict__ attnm,
                                                   const float* __restrict__ projw,
                                                   const float* __restrict__ attn4p,
                                                   u16* __restrict__ cmbh,
                                                   u16* __restrict__ cmbl) {
  int b = blockIdx.x, tid = threadIdx.x;
  __shared__ float att_s[2048], score_s[2048];
  for (int i = tid; i < 2048; i += 128) att_s[i] = attnm[(long)b * 2048 + i];
  __syncthreads();
  {
    int h = tid >> 4, c = tid & 15;
    float v[16], t[16];
    #pragma unroll
    for (int d = 0; d < 16; ++d) { v[d] = att_s[(h * 16 + c) * 16 + d]; t[d] = v[d]; }
    float thr = 0.f, M = -1e30f;
    for (int it = 0; it < 14; ++it) {
      float m = -1e30f; int mi = 0;
      #pragma unroll
      for (int d = 0; d < 16; ++d) if (t[d] > m) { m = t[d]; mi = d; }
      if (it == 0) M = m;
      thr = m;
      t[mi] = -1e31f;
    }
    float s = 0.f, e[16];
    #pragma unroll
    for (int d = 0; d < 16; ++d) { e[d] = (v[d] >= thr) ? expf(v[d] - M) : 0.f; s += e[d]; }
    float inv = 1.f / s;
    #pragma unroll
    for (int d = 0; d < 16; ++d) score_s[(h * 16 + c) * 16 + d] = e[d] * inv;
  }
  __syncthreads();
  float a4 = attn4p[0];
  int o = tid;
  for (int hd = 0; hd < 128; ++hd) {
    int h = hd >> 4, d = hd & 15;
    float s = 0.f;
    #pragma unroll
    for (int c = 0; c < 16; ++c)
      s += projw[o * 128 + h * 16 + c] * score_s[(h * 16 + c) * 16 + d];
    float v = a4 * s;
    long oi = ((long)b * 128 + o) * 128 + hd;
    u16 hi = f2bf(v);
    cmbh[oi] = hi;
    cmbl[oi] = f2bf(v - bf2f(hi));
  }
}

extern "C" void kernel_launch(void* const* d_in, const int* in_sizes, int n_in,
                              void* d_out, int out_size, void* d_ws, size_t ws_size,
                              hipStream_t stream) {
  (void)in_sizes; (void)n_in; (void)out_size; (void)ws_size;
  const float* vi        = (const float*)d_in[0];
  const float* ir        = (const float*)d_in[1];
  const float* text_code = (const float*)d_in[2];
  const float* se_w1     = (const float*)d_in[3];
  const float* se_w2     = (const float*)d_in[4];
  const float* conv1x1_w = (const float*)d_in[5];
  const float* conv1x1_b = (const float*)d_in[6];
  const float* conv_out_w= (const float*)d_in[7];
  const float* conv_out_b= (const float*)d_in[8];
  const float* text_w1   = (const float*)d_in[9];
  const float* text_b1   = (const float*)d_in[10];
  const float* text_w2   = (const float*)d_in[11];
  const float* text_b2   = (const float*)d_in[12];
  const float* norm1_w   = (const float*)d_in[13];
  const float* norm1_b   = (const float*)d_in[14];
  const float* norm2_w   = (const float*)d_in[15];
  const float* norm2_b   = (const float*)d_in[16];
  const float* norm3_w   = (const float*)d_in[17];
  const float* norm3_b   = (const float*)d_in[18];
  const float* q_w       = (const float*)d_in[19];
  const float* q_dw_w    = (const float*)d_in[20];
  const float* kv_w      = (const float*)d_in[21];
  const float* kv_dw_w   = (const float*)d_in[22];
  const float* temperature = (const float*)d_in[23];
  const float* attn4     = (const float*)d_in[24];
  const float* proj_w    = (const float*)d_in[25];
  const float* ffn_in_w  = (const float*)d_in[26];
  const float* ffn_dw_w  = (const float*)d_in[27];
  const float* ffn_out_w = (const float*)d_in[28];
  float* out0 = (float*)d_out;
  float* out1 = out0 + NP;

  char* W = (char*)d_ws;
  float* sq_f  = (float*)(W + 0);
  int*   idx_i = (int*)(W + 4096);
  int*   sidx_i= (int*)(W + 6144);
  u16*   Mch   = (u16*)(W + 12288);
  u16*   Mcl   = (u16*)(W + 274432);
  float* bcomb = (float*)(W + 536576);
  float* qn_f  = (float*)(W + 538624);
  float* kn_f  = (float*)(W + 540672);
  float* attnm = (float*)(W + 542720);
  u16*   cmbh  = (u16*)(W + 575488);
  u16*   cmbl  = (u16*)(W + 706560);
  float* t1f   = (float*)(W + 834560);
  float* tf_f  = (float*)(W + 842752);
  u16*   W2b   = (u16*)(W + 846848);
  u16*   qwb   = (u16*)(W + 912384);
  u16*   kvwb  = (u16*)(W + 945152);
  u16*   ffnWb = (u16*)(W + (1 << 20));
  u16*   ffnOb = (u16*)(W + (1 << 20) + 174080);
  u16* S    = (u16*)(W + (2 << 20));
  u16* CC   = S;                          // qinT -> xqT (in-place) -> Q spatial
  u16* KD   = S + 512L * N_PIX;           // QT -> ATT
  u16* KVD  = S + 1024L * N_PIX;          // concat -> KVD
  u16* CBF  = S + 1024L * N_PIX;
  u16* X3T  = S + 2048L * N_PIX;          // LN3 out
  u16* XKVT = S + 2560L * N_PIX;          // img2T -> xkvT (in-place); FT4 overlays later
  u16* FT4  = S + 2560L * N_PIX;
  u16* FG4  = S + 5280L * N_PIX;
  u16* KVT  = (u16*)out0;
  u16* ATT  = KD;

  const long SN = 128L * N_PIX;
  const long SN2 = 256L * N_PIX;

  wconv5_k<<<340, 256, 0, stream>>>(conv_out_w, W2b, 32768, q_w, qwb, 16384,
                                    kv_w, kvwb, 32768, ffn_in_w, ffnWb, 87040,
                                    ffn_out_w, ffnOb, 43520);
  squeeze_k<<<dim3(256, 4), 256, 0, stream>>>(vi, ir, sq_f, CBF);
  se_text1_k<<<dim3(65, 4), 256, 0, stream>>>(sq_f, se_w1, se_w2, idx_i,
                                              text_code, text_w1, text_b1, t1f);
  text2_k<<<dim3(32, 4), 256, 0, stream>>>(t1f, text_w2, text_b2, tf_f);
  rank2_k<<<4, 256, 0, stream>>>(tf_f, sidx_i);
  mcomb_k<<<dim3(128, 4), 128, 0, stream>>>(conv_out_w, conv_out_b, conv1x1_w,
                                            conv1x1_b, idx_i, sidx_i, Mch, Mcl, bcomb);
  gemm_dual_k<<<dim3(256, 2, 4), 256, 0, stream>>>(
      W2b, conv_out_b, Mch, Mcl, bcomb, CBF, out1, CC, XKVT);
  lnrow_k<<<dim3(256, 2), 256, 0, stream>>>(CC, XKVT, norm1_w, norm1_b, norm2_w, norm2_b);
  // Q proj / KV proj on transposed activations
  gemm_k<2, 0, 0, 3, 2><<<dim3(256, 1, 4), 256, 0, stream>>>(
      qwb, nullptr, 0, CC, SN, nullptr, 0, KD, SN, 128, 128);
  gemm_k<2, 0, 0, 3, 2><<<dim3(256, 2, 4), 256, 0, stream>>>(
      kvwb, nullptr, 0, XKVT, SN, nullptr, 0, KVT, SN2, 256, 128);
  dw3t2_k<<<12288, 256, 0, stream>>>(KD, q_dw_w, CC, KVT, kv_dw_w, KVD);
  rownorm2_k<<<dim3(256, 4), 256, 0, stream>>>(CC, KVD, qn_f, kn_f);
  float* part = (float*)out0;
  attn_part_k<<<dim3(64, 8, 4), 256, 0, stream>>>(CC, KVD, SN2, part);
  attn_reduce_k<<<32, 256, 0, stream>>>(part, qn_f, kn_f, temperature, attnm);
  score_cmb_k<<<4, 128, 0, stream>>>(attnm, proj_w, attn4, cmbh, cmbl);
  gemm_k<3, 0, 0, 0, 2><<<dim3(256, 1, 4), 256, 0, stream>>>(
      cmbh, cmbl, 128L * 128, KVD + SN, SN2, nullptr, 0, ATT, SN, 128, 128);
  lnt_k<<<dim3(256, 4), 256, 0, stream>>>(ATT, norm3_w, norm3_b, X3T);
  gemm_k<2, 0, 0, 3, 2><<<dim3(256, 6, 4), 256, 0, stream>>>(
      ffnWb, nullptr, 0, X3T, SN, nullptr, 0, FT4, 680L * N_PIX, 680, 128);
  dw3gelu4_k<<<10880, 256, 0, stream>>>(FT4, ffn_dw_w, FG4);
  gemm_k<2, 1, 1, 0, 2><<<dim3(256, 1, 4), 256, 0, stream>>>(
      ffnOb, nullptr, 0, FG4, 340L * N_PIX, ATT, SN,
      out0, SN, 128, 340);
}

// Round 21
// 380.092 us; speedup vs baseline: 1.0271x; 1.0271x over previous
//
#include <hip/hip_runtime.h>

typedef unsigned short u16;
typedef __attribute__((ext_vector_type(8))) short bf16x8;
typedef __attribute__((ext_vector_type(4))) float f32x4;

#define N_PIX 16384
static constexpr long NP = 4L * 128 * N_PIX;

__device__ __forceinline__ float bf2f(u16 h) {
  unsigned u = ((unsigned)h) << 16; float f; __builtin_memcpy(&f, &u, 4); return f;
}
__device__ __forceinline__ u16 f2bf(float f) {
  unsigned u; __builtin_memcpy(&u, &f, 4);
  u = (u + 0x7fffu + ((u >> 16) & 1u)) >> 16; return (u16)u;
}

__device__ __forceinline__ float blockReduceSum256(float v) {
  #pragma unroll
  for (int o = 32; o > 0; o >>= 1) v += __shfl_down(v, o, 64);
  __shared__ float sw[4];
  int lane = threadIdx.x & 63, w = threadIdx.x >> 6;
  if (lane == 0) sw[w] = v;
  __syncthreads();
  return (threadIdx.x == 0) ? (sw[0] + sw[1] + sw[2] + sw[3]) : 0.f;
}

// ---- 5 weight tensors f32 -> bf16 ----
__global__ __launch_bounds__(256) void wconv5_k(const float* __restrict__ a0, u16* __restrict__ o0, long n0,
                                                const float* __restrict__ a1, u16* __restrict__ o1, long n1,
                                                const float* __restrict__ a2, u16* __restrict__ o2, long n2,
                                                const float* __restrict__ a3, u16* __restrict__ o3, long n3,
                                                const float* __restrict__ a4, u16* __restrict__ o4, long n4) {
  long i = (long)blockIdx.x * 256 + threadIdx.x;
  if (i < n0) o0[i] = f2bf(a0[i]);
  if (i < n1) o1[i] = f2bf(a1[i]);
  if (i < n2) o2[i] = f2bf(a2[i]);
  if (i < n3) o3[i] = f2bf(a3[i]);
  if (i < n4) o4[i] = f2bf(a4[i]);
}

// ---- squeeze: mean over HW of concat -> [4,256] f32 ; emit bf16 concat ----
__global__ __launch_bounds__(256) void squeeze_k(const float* __restrict__ vi,
                                                 const float* __restrict__ ir,
                                                 float* __restrict__ sq,
                                                 u16* __restrict__ cbf) {
  int c = blockIdx.x, b = blockIdx.y, tid = threadIdx.x;
  const float* src = (c < 128) ? (vi + ((long)b * 128 + c) * N_PIX)
                               : (ir + ((long)b * 128 + (c - 128)) * N_PIX);
  const f32x4* src4 = (const f32x4*)src;
  u16* dst = cbf + ((long)b * 256 + c) * N_PIX;
  float s = 0.f;
  #pragma unroll
  for (int j = 0; j < 8; ++j) {
    f32x4 v0 = src4[j * 512 + tid * 2];
    f32x4 v1 = src4[j * 512 + tid * 2 + 1];
    s += v0.x + v0.y + v0.z + v0.w + v1.x + v1.y + v1.z + v1.w;
    bf16x8 r;
    r[0] = (short)f2bf(v0.x); r[1] = (short)f2bf(v0.y);
    r[2] = (short)f2bf(v0.z); r[3] = (short)f2bf(v0.w);
    r[4] = (short)f2bf(v1.x); r[5] = (short)f2bf(v1.y);
    r[6] = (short)f2bf(v1.z); r[7] = (short)f2bf(v1.w);
    *(bf16x8*)(dst + j * 2048 + tid * 8) = r;
  }
  float t = blockReduceSum256(s);
  if (tid == 0) sq[b * 256 + c] = t * (1.f / 16384.f);
}

// ---- merged: SE MLP + top128 rank (x==64) | text MLP layer1 (x<64) ----
__global__ __launch_bounds__(256) void se_text1_k(const float* __restrict__ sq,
                                                  const float* __restrict__ sew1,
                                                  const float* __restrict__ sew2,
                                                  int* __restrict__ idx,
                                                  const float* __restrict__ tc,
                                                  const float* __restrict__ tw1,
                                                  const float* __restrict__ tb1,
                                                  float* __restrict__ t1f) {
  int b = blockIdx.y, tid = threadIdx.x;
  __shared__ float sm[544];
  if (blockIdx.x == 64) {
    float* s_sq = sm; float* s_h1 = sm + 256; float* s_cw = sm + 288;
    s_sq[tid] = sq[b * 256 + tid];
    __syncthreads();
    if (tid < 32) {
      float s = 0.f;
      for (int c = 0; c < 256; ++c) s += s_sq[c] * sew1[tid * 256 + c];
      s_h1[tid] = fmaxf(s, 0.f);
    }
    __syncthreads();
    {
      float s = 0.f;
      #pragma unroll
      for (int j = 0; j < 32; ++j) s += s_h1[j] * sew2[tid * 32 + j];
      s_cw[tid] = 1.f / (1.f + expf(-s));
    }
    __syncthreads();
    float my = s_cw[tid];
    int rk = 0;
    for (int c = 0; c < 256; ++c) {
      float o = s_cw[c];
      rk += (o > my) || (o == my && c < tid);
    }
    if (rk < 128) idx[b * 128 + rk] = tid;
  } else {
    float* s_tc = sm;
    int j0 = blockIdx.x * 8;
    s_tc[tid] = tc[b * 512 + tid];
    s_tc[tid + 256] = tc[b * 512 + 256 + tid];
    __syncthreads();
    int w = tid >> 6, lane = tid & 63;
    #pragma unroll
    for (int r = 0; r < 2; ++r) {
      int j = j0 + w * 2 + r;
      const float* wr = tw1 + (long)j * 512;
      float s = 0.f;
      #pragma unroll
      for (int k = 0; k < 8; ++k) s += s_tc[lane + k * 64] * wr[lane + k * 64];
      #pragma unroll
      for (int o = 32; o > 0; o >>= 1) s += __shfl_down(s, o, 64);
      if (lane == 0) t1f[b * 512 + j] = fmaxf(s + tb1[j], 0.f);
    }
  }
}

// ---- text MLP layer2 ----
__global__ __launch_bounds__(256) void text2_k(const float* __restrict__ t1f,
                                               const float* __restrict__ tw2,
                                               const float* __restrict__ tb2,
                                               float* __restrict__ tf) {
  int b = blockIdx.y, j0 = blockIdx.x * 8, tid = threadIdx.x;
  __shared__ float s_t1[512];
  s_t1[tid] = t1f[b * 512 + tid];
  s_t1[tid + 256] = t1f[b * 512 + 256 + tid];
  __syncthreads();
  int w = tid >> 6, lane = tid & 63;
  #pragma unroll
  for (int r = 0; r < 2; ++r) {
    int j = j0 + w * 2 + r;
    const float* wr = tw2 + (long)j * 512;
    float s = 0.f;
    #pragma unroll
    for (int k = 0; k < 8; ++k) s += s_t1[lane + k * 64] * wr[lane + k * 64];
    #pragma unroll
    for (int o = 32; o > 0; o >>= 1) s += __shfl_down(s, o, 64);
    if (lane == 0) tf[b * 256 + j] = s + tb2[j];
  }
}

// ---- argsort-rank of tf -> sidx ----
__global__ __launch_bounds__(256) void rank2_k(const float* __restrict__ tf,
                                               int* __restrict__ sidx) {
  int b = blockIdx.x, tid = threadIdx.x;
  __shared__ float s_tf[256];
  s_tf[tid] = tf[b * 256 + tid];
  __syncthreads();
  float my = s_tf[tid];
  int rk = 0;
  for (int c = 0; c < 256; ++c) {
    float o = s_tf[c];
    rk += (o > my) || (o == my && c < tid);
  }
  sidx[b * 256 + rk] = tid;
}

// ---- fold conv1x1+shuffle+conv_out+select into hi/lo bf16 M_b[128,256] ----
__global__ __launch_bounds__(128) void mcomb_k(const float* __restrict__ w2,
                                               const float* __restrict__ w2b,
                                               const float* __restrict__ w1,
                                               const float* __restrict__ w1b,
                                               const int* __restrict__ idx,
                                               const int* __restrict__ sidx,
                                               u16* __restrict__ mch,
                                               u16* __restrict__ mcl,
                                               float* __restrict__ bcomb) {
  int o = blockIdx.x, b = blockIdx.y, tid = threadIdx.x;
  __shared__ float s_w2[256];
  __shared__ int s_sx[256];
  s_w2[tid] = w2[o * 256 + tid];
  s_w2[tid + 128] = w2[o * 256 + tid + 128];
  s_sx[tid] = sidx[b * 256 + tid] & 255;
  s_sx[tid + 128] = sidx[b * 256 + tid + 128] & 255;
  u16* hrow = mch + ((long)b * 128 + o) * 256;
  u16* lrow = mcl + ((long)b * 128 + o) * 256;
  hrow[tid] = 0; hrow[tid + 128] = 0;
  lrow[tid] = 0; lrow[tid + 128] = 0;
  __syncthreads();
  float s = 0.f;
  for (int j = 0; j < 256; ++j) s += s_w2[j] * w1[s_sx[j] * 128 + tid];
  int cc = idx[b * 128 + tid] & 255;
  u16 hi = f2bf(s);
  hrow[cc] = hi;
  lrow[cc] = f2bf(s - bf2f(hi));
  if (tid == 0) {
    float bb = w2b[o];
    for (int j = 0; j < 256; ++j) bb += s_w2[j] * w1b[s_sx[j]];
    bcomb[b * 128 + o] = bb;
  }
}

// ---- fused dual GEMM: BK=64; outputs out1 f32 spatial + qinT/img2T transposed bf16 ----
__global__ __launch_bounds__(256) void gemm_dual_k(
    const u16* __restrict__ W2b, const float* __restrict__ b2,
    const u16* __restrict__ Mch, const u16* __restrict__ Mcl,
    const float* __restrict__ bc, const u16* __restrict__ Xb,
    float* __restrict__ out1, u16* __restrict__ qinT, u16* __restrict__ img2T) {
  const int N = N_PIX;
  int n0 = blockIdx.x * 64, o0 = blockIdx.y * 64, bz = blockIdx.z, tid = threadIdx.x;
  __shared__ __align__(16) char smem[36864];
  u16* A1  = (u16*)smem;            // [64][72]
  u16* A2h = (u16*)(smem + 9216);
  u16* A2l = (u16*)(smem + 18432);
  u16* Xs  = (u16*)(smem + 27648);
  f32x4 acc1[4], acc2[4];
  #pragma unroll
  for (int i = 0; i < 4; ++i) { acc1[i] = (f32x4){0,0,0,0}; acc2[i] = (f32x4){0,0,0,0}; }
  int wv = tid >> 6, lane = tid & 63;
  int lr = lane & 15, lkq = (lane >> 4) * 8;
  for (int kt = 0; kt < 4; ++kt) {
    int k0 = kt << 6;
    {
      int r = tid >> 2, o = o0 + r;
      #pragma unroll
      for (int cc = 0; cc < 2; ++cc) {
        int col = ((tid & 3) << 3) + cc * 32;
        int k = k0 + col;
        *(bf16x8*)&A1[r * 72 + col] = *(const bf16x8*)(W2b + (long)o * 256 + k);
        *(bf16x8*)&A2h[r * 72 + col] = *(const bf16x8*)(Mch + ((long)bz * 128 + o) * 256 + k);
        *(bf16x8*)&A2l[r * 72 + col] = *(const bf16x8*)(Mcl + ((long)bz * 128 + o) * 256 + k);
      }
    }
    {
      int n = tid & 63;
      const u16* src = Xb + (long)bz * 256 * N + n0 + n;
      #pragma unroll
      for (int cc = 0; cc < 2; ++cc) {
        int kb = ((tid >> 6) << 3) + cc * 32;
        int k = k0 + kb;
        bf16x8 t;
        #pragma unroll
        for (int i = 0; i < 8; ++i) t[i] = (short)src[(long)(k + i) * N];
        *(bf16x8*)&Xs[n * 72 + kb] = t;
      }
    }
    __syncthreads();
    #pragma unroll
    for (int kk = 0; kk < 2; ++kk) {
      int lk = kk * 32 + lkq;
      bf16x8 a1 = *(const bf16x8*)&A1[(wv * 16 + lr) * 72 + lk];
      bf16x8 a2h = *(const bf16x8*)&A2h[(wv * 16 + lr) * 72 + lk];
      bf16x8 a2l = *(const bf16x8*)&A2l[(wv * 16 + lr) * 72 + lk];
      #pragma unroll
      for (int nt = 0; nt < 4; ++nt) {
        bf16x8 bfr = *(const bf16x8*)&Xs[(nt * 16 + lr) * 72 + lk];
        acc1[nt] = __builtin_amdgcn_mfma_f32_16x16x32_bf16(a1, bfr, acc1[nt], 0, 0, 0);
        acc2[nt] = __builtin_amdgcn_mfma_f32_16x16x32_bf16(a2h, bfr, acc2[nt], 0, 0, 0);
        acc2[nt] = __builtin_amdgcn_mfma_f32_16x16x32_bf16(a2l, bfr, acc2[nt], 0, 0, 0);
      }
    }
    __syncthreads();
  }
  // ---- staged epilogue: st1 f32 spatial [o][n]; stq/sti u16 transposed [n][o] ----
  float* st1 = (float*)smem;               // 64*68*4 = 17408B
  u16*  stq = (u16*)(smem + 17408);        // 64*68*2 = 8704B
  u16*  sti = (u16*)(smem + 26112);        // 8704B
  #pragma unroll
  for (int nt = 0; nt < 4; ++nt)
    #pragma unroll
    for (int r4 = 0; r4 < 4; ++r4) {
      int o_l = wv * 16 + (lane >> 4) * 4 + r4;
      int n_l = nt * 16 + (lane & 15);
      float v1 = acc1[nt][r4] + b2[o0 + o_l];
      float v2 = acc2[nt][r4] + bc[bz * 128 + o0 + o_l];
      st1[o_l * 68 + n_l] = v1;
      stq[n_l * 68 + o_l] = f2bf(v2);
      sti[n_l * 68 + o_l] = f2bf(v1);
    }
  __syncthreads();
  {
    int row = tid >> 2, colb = (tid & 3) * 16;
    float* dst = out1 + ((long)bz * 128 + o0 + row) * N + n0 + colb;
    #pragma unroll
    for (int j = 0; j < 4; ++j)
      *(f32x4*)(dst + j * 4) = *(f32x4*)&st1[row * 68 + colb + j * 4];
    u16* dq = qinT + ((long)bz * N_PIX + n0 + row) * 128 + o0 + colb;
    u16* di = img2T + ((long)bz * N_PIX + n0 + row) * 128 + o0 + colb;
    *(bf16x8*)dq = *(bf16x8*)&stq[row * 68 + colb];
    *(bf16x8*)(dq + 8) = *(bf16x8*)&stq[row * 68 + colb + 8];
    *(bf16x8*)di = *(bf16x8*)&sti[row * 68 + colb];
    *(bf16x8*)(di + 8) = *(bf16x8*)&sti[row * 68 + colb + 8];
  }
}

// ---- rowwise LayerNorm, 2 threads/pixel (64 ch each), in-place; y=0:t0, y=1:t1 ----
__global__ __launch_bounds__(256) void lnrow_k(u16* __restrict__ t0, u16* __restrict__ t1,
                                               const float* __restrict__ g1, const float* __restrict__ b1,
                                               const float* __restrict__ g2, const float* __restrict__ b2) {
  int y = blockIdx.y, tid = threadIdx.x;
  u16* buf = y ? t1 : t0;
  const float* g = y ? g2 : g1;
  const float* bb = y ? b2 : b1;
  __shared__ float gs[128], bs[128];
  if (tid < 128) { gs[tid] = g[tid]; bs[tid] = bb[tid]; }
  __syncthreads();
  long p = (long)blockIdx.x * 128 + (tid >> 1);   // 65536 pixels / 128 per block
  int half = (tid & 1) * 64;
  u16* src = buf + p * 128 + half;
  bf16x8 v[8];
  float sum = 0.f, sq = 0.f;
  #pragma unroll
  for (int j = 0; j < 8; ++j) {
    v[j] = *(const bf16x8*)(src + j * 8);
    #pragma unroll
    for (int i = 0; i < 8; ++i) { float f = bf2f((u16)v[j][i]); sum += f; sq += f * f; }
  }
  sum += __shfl_xor(sum, 1, 64);
  sq  += __shfl_xor(sq, 1, 64);
  float mu = sum * (1.f / 128.f);
  float var = sq * (1.f / 128.f) - mu * mu;
  float rs = rsqrtf(fmaxf(var, 0.f) + 1e-5f);
  #pragma unroll
  for (int j = 0; j < 8; ++j) {
    bf16x8 r;
    #pragma unroll
    for (int i = 0; i < 8; ++i) {
      float f = bf2f((u16)v[j][i]);
      r[i] = (short)f2bf((f - mu) * rs * gs[half + j * 8 + i] + bs[half + j * 8 + i]);
    }
    *(bf16x8*)(src + j * 8) = r;
  }
}

// ---------------- generic MFMA GEMM, OT o-tiles of 64 rows, coalesced epilogue ----------------
// AMODE: 2=bf16 W, 3=per-batch bf16 hi/lo.
// XT: 0=spatial X via LDS k-gather; 3=transposed X via LDS + DIRECT A (K==128)
template<int AMODE, int RESADD, int OUTF, int XT, int OT>
__global__ __launch_bounds__(256) void gemm_k(
    const u16* __restrict__ Ah, const u16* __restrict__ Alo, long a_bstride,
    const u16* __restrict__ X, long x_bstride,
    const u16* __restrict__ res, long res_bstride,
    void* __restrict__ outv, long out_bstride,
    int O, int K) {
  const int N = N_PIX;
  int n0 = blockIdx.x * 64;
  int o0 = blockIdx.y * 64 * OT;
  int bz = blockIdx.z;
  int tid = threadIdx.x;
  int wv = tid >> 6, lane = tid & 63;
  int lr = lane & 15, lkq = (lane >> 4) * 8;
  __shared__ __align__(16) u16 Xs[64][136];
  __shared__ __align__(16) u16 As[(XT == 3) ? 1 : 64][136];
  __shared__ __align__(16) u16 Al[(AMODE == 3) ? 64 : 1][136];
  f32x4 acc[OT][4];
  #pragma unroll
  for (int ot = 0; ot < OT; ++ot)
    #pragma unroll
    for (int i = 0; i < 4; ++i) acc[ot][i] = (f32x4){0.f, 0.f, 0.f, 0.f};

  if (XT == 3) {
    {
      int n = tid >> 2, koff = (tid & 3) << 5;
      const u16* src = X + (long)bz * x_bstride + (long)(n0 + n) * 128 + koff;
      #pragma unroll
      for (int j = 0; j < 4; ++j)
        *(bf16x8*)&Xs[n][koff + j * 8] = *(const bf16x8*)(src + j * 8);
    }
    __syncthreads();
    #pragma unroll
    for (int ot = 0; ot < OT; ++ot) {
      int oc = o0 + ot * 64 + wv * 16 + lr;
      if (oc > O - 1) oc = O - 1;
      const u16* Arow = Ah + (long)oc * 128;
      bf16x8 afr[4];
      #pragma unroll
      for (int kk = 0; kk < 4; ++kk) afr[kk] = *(const bf16x8*)(Arow + kk * 32 + lkq);
      #pragma unroll
      for (int kk = 0; kk < 4; ++kk) {
        int lk = kk * 32 + lkq;
        #pragma unroll
        for (int nt = 0; nt < 4; ++nt) {
          bf16x8 bfr = *(const bf16x8*)&Xs[nt * 16 + lr][lk];
          acc[ot][nt] = __builtin_amdgcn_mfma_f32_16x16x32_bf16(afr[kk], bfr, acc[ot][nt], 0, 0, 0);
        }
      }
    }
    __syncthreads();
  } else {
    int nk = (K + 127) >> 7;
    for (int kt = 0; kt < nk; ++kt) {
      int k0 = kt << 7;
      {
        int n = tid & 63;
        const u16* src = X + (long)bz * x_bstride + n0 + n;
        #pragma unroll
        for (int cc = 0; cc < 4; ++cc) {
          int kb = ((tid >> 6) << 3) + cc * 32;
          int k = k0 + kb;
          bf16x8 t;
          #pragma unroll
          for (int i = 0; i < 8; ++i)
            t[i] = (short)((k + i < K) ? src[(long)(k + i) * N] : (u16)0);
          *(bf16x8*)&Xs[n][kb] = t;
        }
      }
      #pragma unroll
      for (int ot = 0; ot < OT; ++ot) {
        {
          int r = tid >> 2, o = o0 + ot * 64 + r;
          #pragma unroll
          for (int cc = 0; cc < 4; ++cc) {
            int col = ((tid & 3) << 3) + cc * 32;
            int k = k0 + col;
            if (AMODE == 2) {
              bf16x8 t;
              if (o < O && k + 8 <= K) {
                t = *(const bf16x8*)(Ah + (long)o * K + k);
              } else {
                #pragma unroll
                for (int i = 0; i < 8; ++i)
                  t[i] = (short)((o < O && k + i < K) ? Ah[(long)o * K + k + i] : (u16)0);
              }
              *(bf16x8*)&As[r][col] = t;
            } else {
              long base = (long)bz * a_bstride + (long)o * K + k;
              *(bf16x8*)&As[r][col] = *(const bf16x8*)(Ah + base);
              *(bf16x8*)&Al[r][col] = *(const bf16x8*)(Alo + base);
            }
          }
        }
        __syncthreads();
        #pragma unroll
        for (int kk = 0; kk < 4; ++kk) {
          int lk = kk * 32 + lkq;
          bf16x8 afr = *(const bf16x8*)&As[wv * 16 + lr][lk];
          bf16x8 alr;
          if (AMODE == 3) alr = *(const bf16x8*)&Al[wv * 16 + lr][lk];
          #pragma unroll
          for (int nt = 0; nt < 4; ++nt) {
            bf16x8 bfr = *(const bf16x8*)&Xs[nt * 16 + lr][lk];
            acc[ot][nt] = __builtin_amdgcn_mfma_f32_16x16x32_bf16(afr, bfr, acc[ot][nt], 0, 0, 0);
            if (AMODE == 3)
              acc[ot][nt] = __builtin_amdgcn_mfma_f32_16x16x32_bf16(alr, bfr, acc[ot][nt], 0, 0, 0);
          }
        }
        __syncthreads();
      }
    }
  }

  // ---- coalesced epilogue per o-tile ----
  #pragma unroll
  for (int ot = 0; ot < OT; ++ot) {
    if (ot > 0) __syncthreads();
    if (OUTF == 0) {
      u16* st = &Xs[0][0];
      #pragma unroll
      for (int nt = 0; nt < 4; ++nt)
        #pragma unroll
        for (int r4 = 0; r4 < 4; ++r4) {
          int row = wv * 16 + (lane >> 4) * 4 + r4;
          int col = nt * 16 + (lane & 15);
          st[row * 68 + col] = f2bf(acc[ot][nt][r4]);
        }
      __syncthreads();
      #pragma unroll
      for (int it = 0; it < 2; ++it) {
        int row = (tid >> 3) + it * 32;
        int col = (tid & 7) * 8;
        int o = o0 + ot * 64 + row;
        if (o < O) {
          bf16x8 v = *(bf16x8*)&st[row * 68 + col];
          *(bf16x8*)((u16*)outv + (long)bz * out_bstride + (long)o * N + n0 + col) = v;
        }
      }
    } else {
      float* st = (float*)&Xs[0][0];
      #pragma unroll
      for (int nt = 0; nt < 4; ++nt)
        #pragma unroll
        for (int r4 = 0; r4 < 4; ++r4) {
          int row = wv * 16 + (lane >> 4) * 4 + r4;
          int col = nt * 16 + (lane & 15);
          st[row * 68 + col] = acc[ot][nt][r4];
        }
      __syncthreads();
      {
        int row = tid >> 2, colb = (tid & 3) * 16;
        int o = o0 + ot * 64 + row;
        if (o < O) {
          float* dst = (float*)outv + (long)bz * out_bstride + (long)o * N + n0 + colb;
          bf16x8 rv0, rv1;
          if (RESADD) {
            const u16* rp = res + (long)bz * res_bstride + (long)o * N + n0 + colb;
            rv0 = *(const bf16x8*)rp;
            rv1 = *(const bf16x8*)(rp + 8);
          }
          #pragma unroll
          for (int j = 0; j < 4; ++j) {
            f32x4 v = *(f32x4*)&st[row * 68 + colb + j * 4];
            if (RESADD) {
              #pragma unroll
              for (int i = 0; i < 4; ++i) {
                int idx = j * 4 + i;
                u16 rr = (u16)((idx < 8) ? rv0[idx] : rv1[idx - 8]);
                v[i] += bf2f(rr);
              }
            }
            *(f32x4*)(dst + j * 4) = v;
          }
        }
      }
    }
  }
}

// ---- LN3: bf16 spatial in, TRANSPOSED bf16 out ----
__global__ __launch_bounds__(256) void lnt_k(const u16* __restrict__ in,
                                             const float* __restrict__ gamma,
                                             const float* __restrict__ beta,
                                             u16* __restrict__ outT) {
  int p0 = blockIdx.x * 64, b = blockIdx.y, tid = threadIdx.x;
  int px = tid & 63, g4 = tid >> 6;
  __shared__ float tile[128][65];
  __shared__ float red[8][64];
  __shared__ float gmm[128], bta[128], mu_s[64], rs_s[64];
  if (tid < 128) { gmm[tid] = gamma[tid]; bta[tid] = beta[tid]; }
  long bofs = (long)b * 128 * N_PIX;
  float s = 0.f;
  for (int c = g4; c < 128; c += 4) {
    float v = bf2f(in[bofs + (long)c * N_PIX + p0 + px]);
    tile[c][px] = v;
    s += v;
  }
  red[g4][px] = s;
  __syncthreads();
  if (g4 == 0) mu_s[px] = (red[0][px] + red[1][px] + red[2][px] + red[3][px]) * (1.f / 128.f);
  __syncthreads();
  float mu = mu_s[px];
  float s2 = 0.f;
  for (int c = g4; c < 128; c += 4) { float d = tile[c][px] - mu; s2 += d * d; }
  red[4 + g4][px] = s2;
  __syncthreads();
  if (g4 == 0) {
    float var = (red[4][px] + red[5][px] + red[6][px] + red[7][px]) * (1.f / 128.f);
    rs_s[px] = rsqrtf(var + 1e-5f);
  }
  __syncthreads();
  float rs = rs_s[px];
  for (int c = g4; c < 128; c += 4)
    tile[c][px] = (tile[c][px] - mu) * rs * gmm[c] + bta[c];
  __syncthreads();
  int px2 = tid >> 2, c0 = (tid & 3) << 5;
  u16* dst = outT + ((long)b * N_PIX + p0 + px2) * 128 + c0;
  #pragma unroll
  for (int j = 0; j < 4; ++j) {
    bf16x8 r;
    #pragma unroll
    for (int i = 0; i < 8; ++i) r[i] = (short)f2bf(tile[c0 + j * 8 + i][px2]);
    *(bf16x8*)(dst + j * 8) = r;
  }
}

// ---- merged LDS-tiled depthwise 3x3: planes 0..511 = Q, 512..1535 = KV ----
__global__ __launch_bounds__(256) void dw3t2_k(const u16* __restrict__ inQ,
                                               const float* __restrict__ wQ,
                                               u16* __restrict__ outQ,
                                               const u16* __restrict__ inKV,
                                               const float* __restrict__ wKV,
                                               u16* __restrict__ outKV) {
  int gp = blockIdx.x >> 3, stripe = blockIdx.x & 7, tid = threadIdx.x;
  const u16* in; const float* w; u16* out; int c; long pbase;
  if (gp < 512) { in = inQ;  w = wQ;  out = outQ;  c = gp & 127;  pbase = (long)gp * N_PIX; }
  else { int p2 = gp - 512; in = inKV; w = wKV; out = outKV; c = p2 & 255; pbase = (long)p2 * N_PIX; }
  int y0 = stripe * 16;
  __shared__ __align__(16) u16 tile[18][136];
  for (int v = tid; v < 288; v += 256) {
    int r = v >> 4, col = (v & 15) << 3;
    int y = y0 - 1 + r;
    bf16x8 t;
    #pragma unroll
    for (int i = 0; i < 8; ++i) t[i] = 0;
    if (y >= 0 && y < 128) t = *(const bf16x8*)(in + pbase + y * 128 + col);
    *(bf16x8*)&tile[r][col] = t;
  }
  float wv[9];
  #pragma unroll
  for (int j = 0; j < 9; ++j) wv[j] = w[c * 9 + j];
  __syncthreads();
  int row = tid >> 4, col0 = (tid & 15) << 3;
  float a[3][10];
  #pragma unroll
  for (int dr = 0; dr < 3; ++dr)
    #pragma unroll
    for (int i = 0; i < 10; ++i) {
      int x = col0 - 1 + i;
      a[dr][i] = (x >= 0 && x < 128) ? bf2f(tile[row + dr][x]) : 0.f;
    }
  bf16x8 res;
  #pragma unroll
  for (int j = 0; j < 8; ++j) {
    float s = 0.f;
    #pragma unroll
    for (int dr = 0; dr < 3; ++dr)
      #pragma unroll
      for (int dx = 0; dx < 3; ++dx) s += wv[dr * 3 + dx] * a[dr][j + dx];
    res[j] = (short)f2bf(s);
  }
  *(bf16x8*)(out + pbase + (y0 + row) * 128 + col0) = res;
}

// ---- batched LDS-tiled FFN tail ----
__global__ __launch_bounds__(256) void dw3gelu4_k(const u16* __restrict__ ft,
                                                  const float* __restrict__ w,
                                                  u16* __restrict__ fg) {
  int plane = blockIdx.x >> 3, stripe = blockIdx.x & 7, tid = threadIdx.x;
  int b = plane / 340, c = plane % 340;
  const u16* t1 = ft + ((long)b * 680 + c) * N_PIX;
  const u16* t2 = ft + ((long)b * 680 + 340 + c) * N_PIX;
  u16* g = fg + ((long)b * 340 + c) * N_PIX;
  int y0 = stripe * 16;
  __shared__ __align__(16) u16 ta[18][136];
  __shared__ __align__(16) u16 tb[18][136];
  for (int v = tid; v < 288; v += 256) {
    int r = v >> 4, col = (v & 15) << 3;
    int y = y0 - 1 + r;
    bf16x8 u1, u2;
    #pragma unroll
    for (int i = 0; i < 8; ++i) { u1[i] = 0; u2[i] = 0; }
    if (y >= 0 && y < 128) {
      u1 = *(const bf16x8*)(t1 + y * 128 + col);
      u2 = *(const bf16x8*)(t2 + y * 128 + col);
    }
    *(bf16x8*)&ta[r][col] = u1;
    *(bf16x8*)&tb[r][col] = u2;
  }
  float w1[9], w2[9];
  #pragma unroll
  for (int j = 0; j < 9; ++j) { w1[j] = w[c * 9 + j]; w2[j] = w[(340 + c) * 9 + j]; }
  __syncthreads();
  int row = tid >> 4, col0 = (tid & 15) << 3;
  float a[3][10], bb[3][10];
  #pragma unroll
  for (int dr = 0; dr < 3; ++dr)
    #pragma unroll
    for (int i = 0; i < 10; ++i) {
      int x = col0 - 1 + i;
      bool ok = (x >= 0 && x < 128);
      a[dr][i] = ok ? bf2f(ta[row + dr][x]) : 0.f;
      bb[dr][i] = ok ? bf2f(tb[row + dr][x]) : 0.f;
    }
  bf16x8 res;
  #pragma unroll
  for (int j = 0; j < 8; ++j) {
    float s1 = 0.f, s2 = 0.f;
    #pragma unroll
    for (int dr = 0; dr < 3; ++dr)
      #pragma unroll
      for (int dx = 0; dx < 3; ++dx) {
        s1 += w1[dr * 3 + dx] * a[dr][j + dx];
        s2 += w2[dr * 3 + dx] * bb[dr][j + dx];
      }
    float gl = 0.5f * s1 * (1.f + erff(s1 * 0.70710678118f));
    res[j] = (short)f2bf(gl * s2);
  }
  *(bf16x8*)(g + (y0 + row) * 128 + col0) = res;
}

// ---- merged row L2 norms ----
__global__ __launch_bounds__(256) void rownorm2_k(const u16* __restrict__ q,
                                                  const u16* __restrict__ kv,
                                                  float* __restrict__ qn,
                                                  float* __restrict__ kn) {
  int x = blockIdx.x, b = blockIdx.y, tid = threadIdx.x;
  const u16* src;
  float* dst;
  if (x < 128) { src = q + (long)b * 128 * N_PIX + (long)x * N_PIX; dst = qn + b * 128 + x; }
  else { int r = x - 128; src = kv + (long)b * 256 * N_PIX + (long)r * N_PIX; dst = kn + b * 128 + r; }
  float s = 0.f;
  #pragma unroll
  for (int j = 0; j < 8; ++j) {
    bf16x8 v = *(const bf16x8*)(src + j * 2048 + tid * 8);
    #pragma unroll
    for (int i = 0; i < 8; ++i) { float f = bf2f((u16)v[i]); s += f * f; }
  }
  float t = blockReduceSum256(s);
  if (tid == 0) *dst = sqrtf(t);
}

// ---- attn partials ----
__global__ __launch_bounds__(256) void attn_part_k(const u16* __restrict__ q,
                                                   const u16* __restrict__ kbase,
                                                   long kbstride,
                                                   float* __restrict__ part) {
  int ch = blockIdx.x, h = blockIdx.y, b = blockIdx.z, tid = threadIdx.x;
  int n0 = ch * 256;
  __shared__ __align__(16) u16 qc[16][280];
  __shared__ __align__(16) u16 kc[16][280];
  #pragma unroll
  for (int j = 0; j < 2; ++j) {
    int v = tid + j * 256;
    int r = v >> 5, col = (v & 31) << 3;
    *(bf16x8*)&qc[r][col] = *(const bf16x8*)(q + ((long)b * 128 + h * 16 + r) * N_PIX + n0 + col);
    *(bf16x8*)&kc[r][col] = *(const bf16x8*)(kbase + (long)b * kbstride + (long)(h * 16 + r) * N_PIX + n0 + col);
  }
  __syncthreads();
  int c = tid >> 4, d = tid & 15;
  float acc = 0.f;
  #pragma unroll 4
  for (int nb = 0; nb < 32; ++nb) {
    bf16x8 qv = *(const bf16x8*)&qc[c][nb * 8];
    bf16x8 kv = *(const bf16x8*)&kc[d][nb * 8];
    #pragma unroll
    for (int i = 0; i < 8; ++i) acc += bf2f((u16)qv[i]) * bf2f((u16)kv[i]);
  }
  part[(long)((((b * 8 + h) * 16 + c) * 16 + d)) * 64 + ch] = acc;
}

// ---- reduce partials + cosine scaling ----
__global__ __launch_bounds__(256) void attn_reduce_k(const float* __restrict__ part,
                                                     const float* __restrict__ qn,
                                                     const float* __restrict__ kn,
                                                     const float* __restrict__ temp,
                                                     float* __restrict__ attnm) {
  int idx = blockIdx.x * 256 + threadIdx.x;
  const float* p = part + (long)idx * 64;
  float s = 0.f;
  #pragma unroll
  for (int j = 0; j < 64; ++j) s += p[j];
  int d = idx & 15, c = (idx >> 4) & 15, h = (idx >> 8) & 7, b = idx >> 11;
  float nq = fmaxf(qn[b * 128 + h * 16 + c], 1e-12f);
  float nk = fmaxf(kn[b * 128 + h * 16 + d], 1e-12f);
  attnm[idx] = s / (nq * nk) * temp[h];
}

// ---- top14 threshold + softmax + fold proj into hi/lo Cmb ----
__global__ __launch_bounds__(128) void score_cmb_k(const float* __restrict__ attnm,
                                                   const float* __restrict__ projw,
                                                   const float* __restrict__ attn4p,
                                                   u16* __restrict__ cmbh,
                                                   u16* __restrict__ cmbl) {
  int b = blockIdx.x, tid = threadIdx.x;
  __shared__ float att_s[2048], score_s[2048];
  for (int i = tid; i < 2048; i += 128) att_s[i] = attnm[(long)b * 2048 + i];
  __syncthreads();
  {
    int h = tid >> 4, c = tid & 15;
    float v[16], t[16];
    #pragma unroll
    for (int d = 0; d < 16; ++d) { v[d] = att_s[(h * 16 + c) * 16 + d]; t[d] = v[d]; }
    float thr = 0.f, M = -1e30f;
    for (int it = 0; it < 14; ++it) {
      float m = -1e30f; int mi = 0;
      #pragma unroll
      for (int d = 0; d < 16; ++d) if (t[d] > m) { m = t[d]; mi = d; }
      if (it == 0) M = m;
      thr = m;
      t[mi] = -1e31f;
    }
    float s = 0.f, e[16];
    #pragma unroll
    for (int d = 0; d < 16; ++d) { e[d] = (v[d] >= thr) ? expf(v[d] - M) : 0.f; s += e[d]; }
    float inv = 1.f / s;
    #pragma unroll
    for (int d = 0; d < 16; ++d) score_s[(h * 16 + c) * 16 + d] = e[d] * inv;
  }
  __syncthreads();
  float a4 = attn4p[0];
  int o = tid;
  for (int hd = 0; hd < 128; ++hd) {
    int h = hd >> 4, d = hd & 15;
    float s = 0.f;
    #pragma unroll
    for (int c = 0; c < 16; ++c)
      s += projw[o * 128 + h * 16 + c] * score_s[(h * 16 + c) * 16 + d];
    float v = a4 * s;
    long oi = ((long)b * 128 + o) * 128 + hd;
    u16 hi = f2bf(v);
    cmbh[oi] = hi;
    cmbl[oi] = f2bf(v - bf2f(hi));
  }
}

extern "C" void kernel_launch(void* const* d_in, const int* in_sizes, int n_in,
                              void* d_out, int out_size, void* d_ws, size_t ws_size,
                              hipStream_t stream) {
  (void)in_sizes; (void)n_in; (void)out_size; (void)ws_size;
  const float* vi        = (const float*)d_in[0];
  const float* ir        = (const float*)d_in[1];
  const float* text_code = (const float*)d_in[2];
  const float* se_w1     = (const float*)d_in[3];
  const float* se_w2     = (const float*)d_in[4];
  const float* conv1x1_w = (const float*)d_in[5];
  const float* conv1x1_b = (const float*)d_in[6];
  const float* conv_out_w= (const float*)d_in[7];
  const float* conv_out_b= (const float*)d_in[8];
  const float* text_w1   = (const float*)d_in[9];
  const float* text_b1   = (const float*)d_in[10];
  const float* text_w2   = (const float*)d_in[11];
  const float* text_b2   = (const float*)d_in[12];
  const float* norm1_w   = (const float*)d_in[13];
  const float* norm1_b   = (const float*)d_in[14];
  const float* norm2_w   = (const float*)d_in[15];
  const float* norm2_b   = (const float*)d_in[16];
  const float* norm3_w   = (const float*)d_in[17];
  const float* norm3_b   = (const float*)d_in[18];
  const float* q_w       = (const float*)d_in[19];
  const float* q_dw_w    = (const float*)d_in[20];
  const float* kv_w      = (const float*)d_in[21];
  const float* kv_dw_w   = (const float*)d_in[22];
  const float* temperature = (const float*)d_in[23];
  const float* attn4     = (const float*)d_in[24];
  const float* proj_w    = (const float*)d_in[25];
  const float* ffn_in_w  = (const float*)d_in[26];
  const float* ffn_dw_w  = (const float*)d_in[27];
  const float* ffn_out_w = (const float*)d_in[28];
  float* out0 = (float*)d_out;
  float* out1 = out0 + NP;

  char* W = (char*)d_ws;
  float* sq_f  = (float*)(W + 0);
  int*   idx_i = (int*)(W + 4096);
  int*   sidx_i= (int*)(W + 6144);
  u16*   Mch   = (u16*)(W + 12288);
  u16*   Mcl   = (u16*)(W + 274432);
  float* bcomb = (float*)(W + 536576);
  float* qn_f  = (float*)(W + 538624);
  float* kn_f  = (float*)(W + 540672);
  float* attnm = (float*)(W + 542720);
  u16*   cmbh  = (u16*)(W + 575488);
  u16*   cmbl  = (u16*)(W + 706560);
  float* t1f   = (float*)(W + 834560);
  float* tf_f  = (float*)(W + 842752);
  u16*   W2b   = (u16*)(W + 846848);
  u16*   qwb   = (u16*)(W + 912384);
  u16*   kvwb  = (u16*)(W + 945152);
  u16*   ffnWb = (u16*)(W + (1 << 20));
  u16*   ffnOb = (u16*)(W + (1 << 20) + 174080);
  u16* S    = (u16*)(W + (2 << 20));
  u16* CC   = S;                          // qinT -> xqT (in-place) -> Q spatial
  u16* KD   = S + 512L * N_PIX;           // QT -> ATT
  u16* KVD  = S + 1024L * N_PIX;          // concat -> KVD
  u16* CBF  = S + 1024L * N_PIX;
  u16* X3T  = S + 2048L * N_PIX;          // LN3 out
  u16* XKVT = S + 2560L * N_PIX;          // img2T -> xkvT (in-place); FT4 overlays later
  u16* FT4  = S + 2560L * N_PIX;
  u16* FG4  = S + 5280L * N_PIX;
  u16* KVT  = (u16*)out0;
  u16* ATT  = KD;

  const long SN = 128L * N_PIX;
  const long SN2 = 256L * N_PIX;

  wconv5_k<<<340, 256, 0, stream>>>(conv_out_w, W2b, 32768, q_w, qwb, 16384,
                                    kv_w, kvwb, 32768, ffn_in_w, ffnWb, 87040,
                                    ffn_out_w, ffnOb, 43520);
  squeeze_k<<<dim3(256, 4), 256, 0, stream>>>(vi, ir, sq_f, CBF);
  se_text1_k<<<dim3(65, 4), 256, 0, stream>>>(sq_f, se_w1, se_w2, idx_i,
                                              text_code, text_w1, text_b1, t1f);
  text2_k<<<dim3(32, 4), 256, 0, stream>>>(t1f, text_w2, text_b2, tf_f);
  rank2_k<<<4, 256, 0, stream>>>(tf_f, sidx_i);
  mcomb_k<<<dim3(128, 4), 128, 0, stream>>>(conv_out_w, conv_out_b, conv1x1_w,
                                            conv1x1_b, idx_i, sidx_i, Mch, Mcl, bcomb);
  gemm_dual_k<<<dim3(256, 2, 4), 256, 0, stream>>>(
      W2b, conv_out_b, Mch, Mcl, bcomb, CBF, out1, CC, XKVT);
  lnrow_k<<<dim3(512, 2), 256, 0, stream>>>(CC, XKVT, norm1_w, norm1_b, norm2_w, norm2_b);
  // Q proj / KV proj on transposed activations
  gemm_k<2, 0, 0, 3, 2><<<dim3(256, 1, 4), 256, 0, stream>>>(
      qwb, nullptr, 0, CC, SN, nullptr, 0, KD, SN, 128, 128);
  gemm_k<2, 0, 0, 3, 2><<<dim3(256, 2, 4), 256, 0, stream>>>(
      kvwb, nullptr, 0, XKVT, SN, nullptr, 0, KVT, SN2, 256, 128);
  dw3t2_k<<<12288, 256, 0, stream>>>(KD, q_dw_w, CC, KVT, kv_dw_w, KVD);
  rownorm2_k<<<dim3(256, 4), 256, 0, stream>>>(CC, KVD, qn_f, kn_f);
  float* part = (float*)out0;
  attn_part_k<<<dim3(64, 8, 4), 256, 0, stream>>>(CC, KVD, SN2, part);
  attn_reduce_k<<<32, 256, 0, stream>>>(part, qn_f, kn_f, temperature, attnm);
  score_cmb_k<<<4, 128, 0, stream>>>(attnm, proj_w, attn4, cmbh, cmbl);
  gemm_k<3, 0, 0, 0, 2><<<dim3(256, 1, 4), 256, 0, stream>>>(
      cmbh, cmbl, 128L * 128, KVD + SN, SN2, nullptr, 0, ATT, SN, 128, 128);
  lnt_k<<<dim3(256, 4), 256, 0, stream>>>(ATT, norm3_w, norm3_b, X3T);
  gemm_k<2, 0, 0, 3, 2><<<dim3(256, 6, 4), 256, 0, stream>>>(
      ffnWb, nullptr, 0, X3T, SN, nullptr, 0, FT4, 680L * N_PIX, 680, 128);
  dw3gelu4_k<<<10880, 256, 0, stream>>>(FT4, ffn_dw_w, FG4);
  gemm_k<2, 1, 1, 0, 2><<<dim3(256, 1, 4), 256, 0, stream>>>(
      ffnOb, nullptr, 0, FG4, 340L * N_PIX, ATT, SN,
      out0, SN, 128, 340);
}

// Round 22
// 356.667 us; speedup vs baseline: 1.0945x; 1.0657x over previous
//
#include <hip/hip_runtime.h>

typedef unsigned short u16;
typedef __attribute__((ext_vector_type(8))) short bf16x8;
typedef __attribute__((ext_vector_type(4))) float f32x4;

#define N_PIX 16384
static constexpr long NP = 4L * 128 * N_PIX;

__device__ __forceinline__ float bf2f(u16 h) {
  unsigned u = ((unsigned)h) << 16; float f; __builtin_memcpy(&f, &u, 4); return f;
}
__device__ __forceinline__ u16 f2bf(float f) {
  unsigned u; __builtin_memcpy(&u, &f, 4);
  u = (u + 0x7fffu + ((u >> 16) & 1u)) >> 16; return (u16)u;
}

__device__ __forceinline__ float blockReduceSum256(float v) {
  #pragma unroll
  for (int o = 32; o > 0; o >>= 1) v += __shfl_down(v, o, 64);
  __shared__ float sw[4];
  int lane = threadIdx.x & 63, w = threadIdx.x >> 6;
  if (lane == 0) sw[w] = v;
  __syncthreads();
  return (threadIdx.x == 0) ? (sw[0] + sw[1] + sw[2] + sw[3]) : 0.f;
}

// ---- 5 weight tensors f32 -> bf16 ----
__global__ __launch_bounds__(256) void wconv5_k(const float* __restrict__ a0, u16* __restrict__ o0, long n0,
                                                const float* __restrict__ a1, u16* __restrict__ o1, long n1,
                                                const float* __restrict__ a2, u16* __restrict__ o2, long n2,
                                                const float* __restrict__ a3, u16* __restrict__ o3, long n3,
                                                const float* __restrict__ a4, u16* __restrict__ o4, long n4) {
  long i = (long)blockIdx.x * 256 + threadIdx.x;
  if (i < n0) o0[i] = f2bf(a0[i]);
  if (i < n1) o1[i] = f2bf(a1[i]);
  if (i < n2) o2[i] = f2bf(a2[i]);
  if (i < n3) o3[i] = f2bf(a3[i]);
  if (i < n4) o4[i] = f2bf(a4[i]);
}

// ---- squeeze: mean over HW of concat -> [4,256] f32 ; emit bf16 concat ----
__global__ __launch_bounds__(256) void squeeze_k(const float* __restrict__ vi,
                                                 const float* __restrict__ ir,
                                                 float* __restrict__ sq,
                                                 u16* __restrict__ cbf) {
  int c = blockIdx.x, b = blockIdx.y, tid = threadIdx.x;
  const float* src = (c < 128) ? (vi + ((long)b * 128 + c) * N_PIX)
                               : (ir + ((long)b * 128 + (c - 128)) * N_PIX);
  const f32x4* src4 = (const f32x4*)src;
  u16* dst = cbf + ((long)b * 256 + c) * N_PIX;
  float s = 0.f;
  #pragma unroll
  for (int j = 0; j < 8; ++j) {
    f32x4 v0 = src4[j * 512 + tid * 2];
    f32x4 v1 = src4[j * 512 + tid * 2 + 1];
    s += v0.x + v0.y + v0.z + v0.w + v1.x + v1.y + v1.z + v1.w;
    bf16x8 r;
    r[0] = (short)f2bf(v0.x); r[1] = (short)f2bf(v0.y);
    r[2] = (short)f2bf(v0.z); r[3] = (short)f2bf(v0.w);
    r[4] = (short)f2bf(v1.x); r[5] = (short)f2bf(v1.y);
    r[6] = (short)f2bf(v1.z); r[7] = (short)f2bf(v1.w);
    *(bf16x8*)(dst + j * 2048 + tid * 8) = r;
  }
  float t = blockReduceSum256(s);
  if (tid == 0) sq[b * 256 + c] = t * (1.f / 16384.f);
}

// ---- merged: SE MLP + top128 rank (x==64) | text MLP layer1 (x<64) ----
__global__ __launch_bounds__(256) void se_text1_k(const float* __restrict__ sq,
                                                  const float* __restrict__ sew1,
                                                  const float* __restrict__ sew2,
                                                  int* __restrict__ idx,
                                                  const float* __restrict__ tc,
                                                  const float* __restrict__ tw1,
                                                  const float* __restrict__ tb1,
                                                  float* __restrict__ t1f) {
  int b = blockIdx.y, tid = threadIdx.x;
  __shared__ float sm[544];
  if (blockIdx.x == 64) {
    float* s_sq = sm; float* s_h1 = sm + 256; float* s_cw = sm + 288;
    s_sq[tid] = sq[b * 256 + tid];
    __syncthreads();
    if (tid < 32) {
      float s = 0.f;
      for (int c = 0; c < 256; ++c) s += s_sq[c] * sew1[tid * 256 + c];
      s_h1[tid] = fmaxf(s, 0.f);
    }
    __syncthreads();
    {
      float s = 0.f;
      #pragma unroll
      for (int j = 0; j < 32; ++j) s += s_h1[j] * sew2[tid * 32 + j];
      s_cw[tid] = 1.f / (1.f + expf(-s));
    }
    __syncthreads();
    float my = s_cw[tid];
    int rk = 0;
    for (int c = 0; c < 256; ++c) {
      float o = s_cw[c];
      rk += (o > my) || (o == my && c < tid);
    }
    if (rk < 128) idx[b * 128 + rk] = tid;
  } else {
    float* s_tc = sm;
    int j0 = blockIdx.x * 8;
    s_tc[tid] = tc[b * 512 + tid];
    s_tc[tid + 256] = tc[b * 512 + 256 + tid];
    __syncthreads();
    int w = tid >> 6, lane = tid & 63;
    #pragma unroll
    for (int r = 0; r < 2; ++r) {
      int j = j0 + w * 2 + r;
      const float* wr = tw1 + (long)j * 512;
      float s = 0.f;
      #pragma unroll
      for (int k = 0; k < 8; ++k) s += s_tc[lane + k * 64] * wr[lane + k * 64];
      #pragma unroll
      for (int o = 32; o > 0; o >>= 1) s += __shfl_down(s, o, 64);
      if (lane == 0) t1f[b * 512 + j] = fmaxf(s + tb1[j], 0.f);
    }
  }
}

// ---- text MLP layer2 ----
__global__ __launch_bounds__(256) void text2_k(const float* __restrict__ t1f,
                                               const float* __restrict__ tw2,
                                               const float* __restrict__ tb2,
                                               float* __restrict__ tf) {
  int b = blockIdx.y, j0 = blockIdx.x * 8, tid = threadIdx.x;
  __shared__ float s_t1[512];
  s_t1[tid] = t1f[b * 512 + tid];
  s_t1[tid + 256] = t1f[b * 512 + 256 + tid];
  __syncthreads();
  int w = tid >> 6, lane = tid & 63;
  #pragma unroll
  for (int r = 0; r < 2; ++r) {
    int j = j0 + w * 2 + r;
    const float* wr = tw2 + (long)j * 512;
    float s = 0.f;
    #pragma unroll
    for (int k = 0; k < 8; ++k) s += s_t1[lane + k * 64] * wr[lane + k * 64];
    #pragma unroll
    for (int o = 32; o > 0; o >>= 1) s += __shfl_down(s, o, 64);
    if (lane == 0) tf[b * 256 + j] = s + tb2[j];
  }
}

// ---- argsort-rank of tf -> sidx ----
__global__ __launch_bounds__(256) void rank2_k(const float* __restrict__ tf,
                                               int* __restrict__ sidx) {
  int b = blockIdx.x, tid = threadIdx.x;
  __shared__ float s_tf[256];
  s_tf[tid] = tf[b * 256 + tid];
  __syncthreads();
  float my = s_tf[tid];
  int rk = 0;
  for (int c = 0; c < 256; ++c) {
    float o = s_tf[c];
    rk += (o > my) || (o == my && c < tid);
  }
  sidx[b * 256 + rk] = tid;
}

// ---- fold conv1x1+shuffle+conv_out+select into hi/lo bf16 M_b[128,256] ----
__global__ __launch_bounds__(128) void mcomb_k(const float* __restrict__ w2,
                                               const float* __restrict__ w2b,
                                               const float* __restrict__ w1,
                                               const float* __restrict__ w1b,
                                               const int* __restrict__ idx,
                                               const int* __restrict__ sidx,
                                               u16* __restrict__ mch,
                                               u16* __restrict__ mcl,
                                               float* __restrict__ bcomb) {
  int o = blockIdx.x, b = blockIdx.y, tid = threadIdx.x;
  __shared__ float s_w2[256];
  __shared__ int s_sx[256];
  s_w2[tid] = w2[o * 256 + tid];
  s_w2[tid + 128] = w2[o * 256 + tid + 128];
  s_sx[tid] = sidx[b * 256 + tid] & 255;
  s_sx[tid + 128] = sidx[b * 256 + tid + 128] & 255;
  u16* hrow = mch + ((long)b * 128 + o) * 256;
  u16* lrow = mcl + ((long)b * 128 + o) * 256;
  hrow[tid] = 0; hrow[tid + 128] = 0;
  lrow[tid] = 0; lrow[tid + 128] = 0;
  __syncthreads();
  float s = 0.f;
  for (int j = 0; j < 256; ++j) s += s_w2[j] * w1[s_sx[j] * 128 + tid];
  int cc = idx[b * 128 + tid] & 255;
  u16 hi = f2bf(s);
  hrow[cc] = hi;
  lrow[cc] = f2bf(s - bf2f(hi));
  if (tid == 0) {
    float bb = w2b[o];
    for (int j = 0; j < 256; ++j) bb += s_w2[j] * w1b[s_sx[j]];
    bcomb[b * 128 + o] = bb;
  }
}

// ---- fused dual GEMM + LN1/LN2: full 128-o per block; outputs out1 f32 spatial,
//      xqT/xkvT transposed bf16 ALREADY LayerNorm'ed ----
__global__ __launch_bounds__(256) void gemm_dual_k(
    const u16* __restrict__ W2b, const float* __restrict__ b2,
    const u16* __restrict__ Mch, const u16* __restrict__ Mcl,
    const float* __restrict__ bc, const u16* __restrict__ Xb,
    float* __restrict__ out1, u16* __restrict__ xqT, u16* __restrict__ xkvT,
    const float* __restrict__ g1, const float* __restrict__ b1,
    const float* __restrict__ g2, const float* __restrict__ b2n) {
  const int N = N_PIX;
  int n0 = blockIdx.x * 64, bz = blockIdx.z, tid = threadIdx.x;
  __shared__ __align__(16) char smem[36864];
  u16* A1  = (u16*)smem;            // [64][72]
  u16* A2h = (u16*)(smem + 9216);
  u16* A2l = (u16*)(smem + 18432);
  u16* Xs  = (u16*)(smem + 27648);
  __shared__ float gs1[128], bs1[128], gs2[128], bs2[128];
  if (tid < 128) { gs1[tid] = g1[tid]; bs1[tid] = b1[tid]; gs2[tid] = g2[tid]; bs2[tid] = b2n[tid]; }
  f32x4 acc1[2][4], acc2[2][4];
  #pragma unroll
  for (int ot = 0; ot < 2; ++ot)
    #pragma unroll
    for (int i = 0; i < 4; ++i) { acc1[ot][i] = (f32x4){0,0,0,0}; acc2[ot][i] = (f32x4){0,0,0,0}; }
  int wv = tid >> 6, lane = tid & 63;
  int lr = lane & 15, lkq = (lane >> 4) * 8;
  for (int kt = 0; kt < 4; ++kt) {
    int k0 = kt << 6;
    {
      int n = tid & 63;
      const u16* src = Xb + (long)bz * 256 * N + n0 + n;
      #pragma unroll
      for (int cc = 0; cc < 2; ++cc) {
        int kb = ((tid >> 6) << 3) + cc * 32;
        int k = k0 + kb;
        bf16x8 t;
        #pragma unroll
        for (int i = 0; i < 8; ++i) t[i] = (short)src[(long)(k + i) * N];
        *(bf16x8*)&Xs[n * 72 + kb] = t;
      }
    }
    #pragma unroll
    for (int ot = 0; ot < 2; ++ot) {
      {
        int r = tid >> 2, o = ot * 64 + r;
        #pragma unroll
        for (int cc = 0; cc < 2; ++cc) {
          int col = ((tid & 3) << 3) + cc * 32;
          int k = k0 + col;
          *(bf16x8*)&A1[r * 72 + col] = *(const bf16x8*)(W2b + (long)o * 256 + k);
          *(bf16x8*)&A2h[r * 72 + col] = *(const bf16x8*)(Mch + ((long)bz * 128 + o) * 256 + k);
          *(bf16x8*)&A2l[r * 72 + col] = *(const bf16x8*)(Mcl + ((long)bz * 128 + o) * 256 + k);
        }
      }
      __syncthreads();
      #pragma unroll
      for (int kk = 0; kk < 2; ++kk) {
        int lk = kk * 32 + lkq;
        bf16x8 a1 = *(const bf16x8*)&A1[(wv * 16 + lr) * 72 + lk];
        bf16x8 a2h = *(const bf16x8*)&A2h[(wv * 16 + lr) * 72 + lk];
        bf16x8 a2l = *(const bf16x8*)&A2l[(wv * 16 + lr) * 72 + lk];
        #pragma unroll
        for (int nt = 0; nt < 4; ++nt) {
          bf16x8 bfr = *(const bf16x8*)&Xs[(nt * 16 + lr) * 72 + lk];
          acc1[ot][nt] = __builtin_amdgcn_mfma_f32_16x16x32_bf16(a1, bfr, acc1[ot][nt], 0, 0, 0);
          acc2[ot][nt] = __builtin_amdgcn_mfma_f32_16x16x32_bf16(a2h, bfr, acc2[ot][nt], 0, 0, 0);
          acc2[ot][nt] = __builtin_amdgcn_mfma_f32_16x16x32_bf16(a2l, bfr, acc2[ot][nt], 0, 0, 0);
        }
      }
      __syncthreads();
    }
  }
  // ---- pass 1: out1 f32 spatial, per o-tile ----
  float* st1 = (float*)smem;   // [64][68] f32 = 17408B
  #pragma unroll
  for (int ot = 0; ot < 2; ++ot) {
    #pragma unroll
    for (int nt = 0; nt < 4; ++nt)
      #pragma unroll
      for (int r4 = 0; r4 < 4; ++r4) {
        int o_l = wv * 16 + (lane >> 4) * 4 + r4;
        int n_l = nt * 16 + (lane & 15);
        st1[o_l * 68 + n_l] = acc1[ot][nt][r4] + b2[ot * 64 + o_l];
      }
    __syncthreads();
    {
      int row = tid >> 2, colb = (tid & 3) * 16;
      float* dst = out1 + ((long)bz * 128 + ot * 64 + row) * N + n0 + colb;
      #pragma unroll
      for (int j = 0; j < 4; ++j)
        *(f32x4*)(dst + j * 4) = *(f32x4*)&st1[row * 68 + colb + j * 4];
    }
    __syncthreads();
  }
  // ---- pass 2: qin transposed + LN1 -> xqT ----
  u16* stq = (u16*)smem;   // [64][132] u16 = 16896B
  #pragma unroll
  for (int ot = 0; ot < 2; ++ot)
    #pragma unroll
    for (int nt = 0; nt < 4; ++nt)
      #pragma unroll
      for (int r4 = 0; r4 < 4; ++r4) {
        int o_a = ot * 64 + wv * 16 + (lane >> 4) * 4 + r4;
        int n_l = nt * 16 + (lane & 15);
        stq[n_l * 132 + o_a] = f2bf(acc2[ot][nt][r4] + bc[bz * 128 + o_a]);
      }
  __syncthreads();
  {
    int n = tid >> 2, c0 = (tid & 3) * 32;
    bf16x8 v[4];
    float sum = 0.f, sq = 0.f;
    #pragma unroll
    for (int j = 0; j < 4; ++j) {
      v[j] = *(const bf16x8*)&stq[n * 132 + c0 + j * 8];
      #pragma unroll
      for (int i = 0; i < 8; ++i) { float f = bf2f((u16)v[j][i]); sum += f; sq += f * f; }
    }
    sum += __shfl_xor(sum, 1, 64); sum += __shfl_xor(sum, 2, 64);
    sq  += __shfl_xor(sq, 1, 64);  sq  += __shfl_xor(sq, 2, 64);
    float mu = sum * (1.f / 128.f);
    float var = sq * (1.f / 128.f) - mu * mu;
    float rs = rsqrtf(fmaxf(var, 0.f) + 1e-5f);
    u16* dst = xqT + ((long)bz * N_PIX + n0 + n) * 128 + c0;
    #pragma unroll
    for (int j = 0; j < 4; ++j) {
      bf16x8 r;
      #pragma unroll
      for (int i = 0; i < 8; ++i) {
        float f = bf2f((u16)v[j][i]);
        r[i] = (short)f2bf((f - mu) * rs * gs1[c0 + j * 8 + i] + bs1[c0 + j * 8 + i]);
      }
      *(bf16x8*)(dst + j * 8) = r;
    }
  }
  __syncthreads();
  // ---- pass 3: img2 transposed + LN2 -> xkvT ----
  #pragma unroll
  for (int ot = 0; ot < 2; ++ot)
    #pragma unroll
    for (int nt = 0; nt < 4; ++nt)
      #pragma unroll
      for (int r4 = 0; r4 < 4; ++r4) {
        int o_a = ot * 64 + wv * 16 + (lane >> 4) * 4 + r4;
        int n_l = nt * 16 + (lane & 15);
        stq[n_l * 132 + o_a] = f2bf(acc1[ot][nt][r4] + b2[o_a]);
      }
  __syncthreads();
  {
    int n = tid >> 2, c0 = (tid & 3) * 32;
    bf16x8 v[4];
    float sum = 0.f, sq = 0.f;
    #pragma unroll
    for (int j = 0; j < 4; ++j) {
      v[j] = *(const bf16x8*)&stq[n * 132 + c0 + j * 8];
      #pragma unroll
      for (int i = 0; i < 8; ++i) { float f = bf2f((u16)v[j][i]); sum += f; sq += f * f; }
    }
    sum += __shfl_xor(sum, 1, 64); sum += __shfl_xor(sum, 2, 64);
    sq  += __shfl_xor(sq, 1, 64);  sq  += __shfl_xor(sq, 2, 64);
    float mu = sum * (1.f / 128.f);
    float var = sq * (1.f / 128.f) - mu * mu;
    float rs = rsqrtf(fmaxf(var, 0.f) + 1e-5f);
    u16* dst = xkvT + ((long)bz * N_PIX + n0 + n) * 128 + c0;
    #pragma unroll
    for (int j = 0; j < 4; ++j) {
      bf16x8 r;
      #pragma unroll
      for (int i = 0; i < 8; ++i) {
        float f = bf2f((u16)v[j][i]);
        r[i] = (short)f2bf((f - mu) * rs * gs2[c0 + j * 8 + i] + bs2[c0 + j * 8 + i]);
      }
      *(bf16x8*)(dst + j * 8) = r;
    }
  }
}

// ---- att GEMM (hi/lo A, spatial V) + fused LN3: outputs ATT bf16 spatial + X3T normalized ----
__global__ __launch_bounds__(256) void att_ln_k(
    const u16* __restrict__ Ah, const u16* __restrict__ Alo,
    const u16* __restrict__ V, long v_bstride,
    u16* __restrict__ att, u16* __restrict__ x3T,
    const float* __restrict__ g3, const float* __restrict__ b3) {
  const int N = N_PIX;
  int n0 = blockIdx.x * 64, bz = blockIdx.z, tid = threadIdx.x;
  int wv = tid >> 6, lane = tid & 63;
  int lr = lane & 15, lkq = (lane >> 4) * 8;
  __shared__ __align__(16) u16 Xs[64][136];
  __shared__ __align__(16) u16 As[64][136];
  __shared__ __align__(16) u16 Al[64][136];
  __shared__ float gs[128], bs[128];
  if (tid < 128) { gs[tid] = g3[tid]; bs[tid] = b3[tid]; }
  f32x4 acc[2][4];
  #pragma unroll
  for (int ot = 0; ot < 2; ++ot)
    #pragma unroll
    for (int i = 0; i < 4; ++i) acc[ot][i] = (f32x4){0.f, 0.f, 0.f, 0.f};
  // stage V (K=128) via k-gather
  {
    int n = tid & 63;
    const u16* src = V + (long)bz * v_bstride + n0 + n;
    #pragma unroll
    for (int cc = 0; cc < 4; ++cc) {
      int kb = ((tid >> 6) << 3) + cc * 32;
      bf16x8 t;
      #pragma unroll
      for (int i = 0; i < 8; ++i) t[i] = (short)src[(long)(kb + i) * N];
      *(bf16x8*)&Xs[n][kb] = t;
    }
  }
  #pragma unroll
  for (int ot = 0; ot < 2; ++ot) {
    {
      int r = tid >> 2, o = ot * 64 + r;
      #pragma unroll
      for (int cc = 0; cc < 4; ++cc) {
        int col = ((tid & 3) << 3) + cc * 32;
        long base = (long)bz * (128L * 128) + (long)o * 128 + col;
        *(bf16x8*)&As[r][col] = *(const bf16x8*)(Ah + base);
        *(bf16x8*)&Al[r][col] = *(const bf16x8*)(Alo + base);
      }
    }
    __syncthreads();
    #pragma unroll
    for (int kk = 0; kk < 4; ++kk) {
      int lk = kk * 32 + lkq;
      bf16x8 afr = *(const bf16x8*)&As[wv * 16 + lr][lk];
      bf16x8 alr = *(const bf16x8*)&Al[wv * 16 + lr][lk];
      #pragma unroll
      for (int nt = 0; nt < 4; ++nt) {
        bf16x8 bfr = *(const bf16x8*)&Xs[nt * 16 + lr][lk];
        acc[ot][nt] = __builtin_amdgcn_mfma_f32_16x16x32_bf16(afr, bfr, acc[ot][nt], 0, 0, 0);
        acc[ot][nt] = __builtin_amdgcn_mfma_f32_16x16x32_bf16(alr, bfr, acc[ot][nt], 0, 0, 0);
      }
    }
    __syncthreads();
  }
  // pass 1: ATT bf16 spatial per o-tile (stage in Xs, stride 68)
  u16* st = &Xs[0][0];
  #pragma unroll
  for (int ot = 0; ot < 2; ++ot) {
    #pragma unroll
    for (int nt = 0; nt < 4; ++nt)
      #pragma unroll
      for (int r4 = 0; r4 < 4; ++r4) {
        int row = wv * 16 + (lane >> 4) * 4 + r4;
        int col = nt * 16 + (lane & 15);
        st[row * 68 + col] = f2bf(acc[ot][nt][r4]);
      }
    __syncthreads();
    #pragma unroll
    for (int it = 0; it < 2; ++it) {
      int row = (tid >> 3) + it * 32;
      int col = (tid & 7) * 8;
      bf16x8 v = *(bf16x8*)&st[row * 68 + col];
      *(bf16x8*)(att + ((long)bz * 128 + ot * 64 + row) * N + n0 + col) = v;
    }
    __syncthreads();
  }
  // pass 2: transposed stage + LN3 -> x3T
  u16* stq = &Xs[0][0];  // reuse as [64][132]
  #pragma unroll
  for (int ot = 0; ot < 2; ++ot)
    #pragma unroll
    for (int nt = 0; nt < 4; ++nt)
      #pragma unroll
      for (int r4 = 0; r4 < 4; ++r4) {
        int o_a = ot * 64 + wv * 16 + (lane >> 4) * 4 + r4;
        int n_l = nt * 16 + (lane & 15);
        stq[n_l * 132 + o_a] = f2bf(acc[ot][nt][r4]);
      }
  __syncthreads();
  {
    int n = tid >> 2, c0 = (tid & 3) * 32;
    bf16x8 v[4];
    float sum = 0.f, sq = 0.f;
    #pragma unroll
    for (int j = 0; j < 4; ++j) {
      v[j] = *(const bf16x8*)&stq[n * 132 + c0 + j * 8];
      #pragma unroll
      for (int i = 0; i < 8; ++i) { float f = bf2f((u16)v[j][i]); sum += f; sq += f * f; }
    }
    sum += __shfl_xor(sum, 1, 64); sum += __shfl_xor(sum, 2, 64);
    sq  += __shfl_xor(sq, 1, 64);  sq  += __shfl_xor(sq, 2, 64);
    float mu = sum * (1.f / 128.f);
    float var = sq * (1.f / 128.f) - mu * mu;
    float rs = rsqrtf(fmaxf(var, 0.f) + 1e-5f);
    u16* dst = x3T + ((long)bz * N_PIX + n0 + n) * 128 + c0;
    #pragma unroll
    for (int j = 0; j < 4; ++j) {
      bf16x8 r;
      #pragma unroll
      for (int i = 0; i < 8; ++i) {
        float f = bf2f((u16)v[j][i]);
        r[i] = (short)f2bf((f - mu) * rs * gs[c0 + j * 8 + i] + bs[c0 + j * 8 + i]);
      }
      *(bf16x8*)(dst + j * 8) = r;
    }
  }
}

// ---------------- generic MFMA GEMM, OT o-tiles of 64 rows, coalesced epilogue ----------------
// AMODE: 2=bf16 W. XT: 0=spatial X via LDS k-gather; 3=transposed X via LDS + DIRECT A (K==128)
template<int AMODE, int RESADD, int OUTF, int XT, int OT>
__global__ __launch_bounds__(256) void gemm_k(
    const u16* __restrict__ Ah, const u16* __restrict__ Alo, long a_bstride,
    const u16* __restrict__ X, long x_bstride,
    const u16* __restrict__ res, long res_bstride,
    void* __restrict__ outv, long out_bstride,
    int O, int K) {
  const int N = N_PIX;
  int n0 = blockIdx.x * 64;
  int o0 = blockIdx.y * 64 * OT;
  int bz = blockIdx.z;
  int tid = threadIdx.x;
  int wv = tid >> 6, lane = tid & 63;
  int lr = lane & 15, lkq = (lane >> 4) * 8;
  __shared__ __align__(16) u16 Xs[64][136];
  __shared__ __align__(16) u16 As[(XT == 3) ? 1 : 64][136];
  f32x4 acc[OT][4];
  #pragma unroll
  for (int ot = 0; ot < OT; ++ot)
    #pragma unroll
    for (int i = 0; i < 4; ++i) acc[ot][i] = (f32x4){0.f, 0.f, 0.f, 0.f};

  if (XT == 3) {
    {
      int n = tid >> 2, koff = (tid & 3) << 5;
      const u16* src = X + (long)bz * x_bstride + (long)(n0 + n) * 128 + koff;
      #pragma unroll
      for (int j = 0; j < 4; ++j)
        *(bf16x8*)&Xs[n][koff + j * 8] = *(const bf16x8*)(src + j * 8);
    }
    __syncthreads();
    #pragma unroll
    for (int ot = 0; ot < OT; ++ot) {
      int oc = o0 + ot * 64 + wv * 16 + lr;
      if (oc > O - 1) oc = O - 1;
      const u16* Arow = Ah + (long)oc * 128;
      bf16x8 afr[4];
      #pragma unroll
      for (int kk = 0; kk < 4; ++kk) afr[kk] = *(const bf16x8*)(Arow + kk * 32 + lkq);
      #pragma unroll
      for (int kk = 0; kk < 4; ++kk) {
        int lk = kk * 32 + lkq;
        #pragma unroll
        for (int nt = 0; nt < 4; ++nt) {
          bf16x8 bfr = *(const bf16x8*)&Xs[nt * 16 + lr][lk];
          acc[ot][nt] = __builtin_amdgcn_mfma_f32_16x16x32_bf16(afr[kk], bfr, acc[ot][nt], 0, 0, 0);
        }
      }
    }
    __syncthreads();
  } else {
    int nk = (K + 127) >> 7;
    for (int kt = 0; kt < nk; ++kt) {
      int k0 = kt << 7;
      {
        int n = tid & 63;
        const u16* src = X + (long)bz * x_bstride + n0 + n;
        #pragma unroll
        for (int cc = 0; cc < 4; ++cc) {
          int kb = ((tid >> 6) << 3) + cc * 32;
          int k = k0 + kb;
          bf16x8 t;
          #pragma unroll
          for (int i = 0; i < 8; ++i)
            t[i] = (short)((k + i < K) ? src[(long)(k + i) * N] : (u16)0);
          *(bf16x8*)&Xs[n][kb] = t;
        }
      }
      #pragma unroll
      for (int ot = 0; ot < OT; ++ot) {
        {
          int r = tid >> 2, o = o0 + ot * 64 + r;
          #pragma unroll
          for (int cc = 0; cc < 4; ++cc) {
            int col = ((tid & 3) << 3) + cc * 32;
            int k = k0 + col;
            bf16x8 t;
            if (o < O && k + 8 <= K) {
              t = *(const bf16x8*)(Ah + (long)o * K + k);
            } else {
              #pragma unroll
              for (int i = 0; i < 8; ++i)
                t[i] = (short)((o < O && k + i < K) ? Ah[(long)o * K + k + i] : (u16)0);
            }
            *(bf16x8*)&As[r][col] = t;
          }
        }
        __syncthreads();
        #pragma unroll
        for (int kk = 0; kk < 4; ++kk) {
          int lk = kk * 32 + lkq;
          bf16x8 afr = *(const bf16x8*)&As[wv * 16 + lr][lk];
          #pragma unroll
          for (int nt = 0; nt < 4; ++nt) {
            bf16x8 bfr = *(const bf16x8*)&Xs[nt * 16 + lr][lk];
            acc[ot][nt] = __builtin_amdgcn_mfma_f32_16x16x32_bf16(afr, bfr, acc[ot][nt], 0, 0, 0);
          }
        }
        __syncthreads();
      }
    }
  }

  // ---- coalesced epilogue per o-tile ----
  #pragma unroll
  for (int ot = 0; ot < OT; ++ot) {
    if (ot > 0) __syncthreads();
    if (OUTF == 0) {
      u16* st = &Xs[0][0];
      #pragma unroll
      for (int nt = 0; nt < 4; ++nt)
        #pragma unroll
        for (int r4 = 0; r4 < 4; ++r4) {
          int row = wv * 16 + (lane >> 4) * 4 + r4;
          int col = nt * 16 + (lane & 15);
          st[row * 68 + col] = f2bf(acc[ot][nt][r4]);
        }
      __syncthreads();
      #pragma unroll
      for (int it = 0; it < 2; ++it) {
        int row = (tid >> 3) + it * 32;
        int col = (tid & 7) * 8;
        int o = o0 + ot * 64 + row;
        if (o < O) {
          bf16x8 v = *(bf16x8*)&st[row * 68 + col];
          *(bf16x8*)((u16*)outv + (long)bz * out_bstride + (long)o * N + n0 + col) = v;
        }
      }
    } else {
      float* st = (float*)&Xs[0][0];
      #pragma unroll
      for (int nt = 0; nt < 4; ++nt)
        #pragma unroll
        for (int r4 = 0; r4 < 4; ++r4) {
          int row = wv * 16 + (lane >> 4) * 4 + r4;
          int col = nt * 16 + (lane & 15);
          st[row * 68 + col] = acc[ot][nt][r4];
        }
      __syncthreads();
      {
        int row = tid >> 2, colb = (tid & 3) * 16;
        int o = o0 + ot * 64 + row;
        if (o < O) {
          float* dst = (float*)outv + (long)bz * out_bstride + (long)o * N + n0 + colb;
          bf16x8 rv0, rv1;
          if (RESADD) {
            const u16* rp = res + (long)bz * res_bstride + (long)o * N + n0 + colb;
            rv0 = *(const bf16x8*)rp;
            rv1 = *(const bf16x8*)(rp + 8);
          }
          #pragma unroll
          for (int j = 0; j < 4; ++j) {
            f32x4 v = *(f32x4*)&st[row * 68 + colb + j * 4];
            if (RESADD) {
              #pragma unroll
              for (int i = 0; i < 4; ++i) {
                int idx = j * 4 + i;
                u16 rr = (u16)((idx < 8) ? rv0[idx] : rv1[idx - 8]);
                v[i] += bf2f(rr);
              }
            }
            *(f32x4*)(dst + j * 4) = v;
          }
        }
      }
    }
  }
}

// ---- merged LDS-tiled depthwise 3x3: planes 0..511 = Q, 512..1535 = KV ----
__global__ __launch_bounds__(256) void dw3t2_k(const u16* __restrict__ inQ,
                                               const float* __restrict__ wQ,
                                               u16* __restrict__ outQ,
                                               const u16* __restrict__ inKV,
                                               const float* __restrict__ wKV,
                                               u16* __restrict__ outKV) {
  int gp = blockIdx.x >> 3, stripe = blockIdx.x & 7, tid = threadIdx.x;
  const u16* in; const float* w; u16* out; int c; long pbase;
  if (gp < 512) { in = inQ;  w = wQ;  out = outQ;  c = gp & 127;  pbase = (long)gp * N_PIX; }
  else { int p2 = gp - 512; in = inKV; w = wKV; out = outKV; c = p2 & 255; pbase = (long)p2 * N_PIX; }
  int y0 = stripe * 16;
  __shared__ __align__(16) u16 tile[18][136];
  for (int v = tid; v < 288; v += 256) {
    int r = v >> 4, col = (v & 15) << 3;
    int y = y0 - 1 + r;
    bf16x8 t;
    #pragma unroll
    for (int i = 0; i < 8; ++i) t[i] = 0;
    if (y >= 0 && y < 128) t = *(const bf16x8*)(in + pbase + y * 128 + col);
    *(bf16x8*)&tile[r][col] = t;
  }
  float wv[9];
  #pragma unroll
  for (int j = 0; j < 9; ++j) wv[j] = w[c * 9 + j];
  __syncthreads();
  int row = tid >> 4, col0 = (tid & 15) << 3;
  float a[3][10];
  #pragma unroll
  for (int dr = 0; dr < 3; ++dr)
    #pragma unroll
    for (int i = 0; i < 10; ++i) {
      int x = col0 - 1 + i;
      a[dr][i] = (x >= 0 && x < 128) ? bf2f(tile[row + dr][x]) : 0.f;
    }
  bf16x8 res;
  #pragma unroll
  for (int j = 0; j < 8; ++j) {
    float s = 0.f;
    #pragma unroll
    for (int dr = 0; dr < 3; ++dr)
      #pragma unroll
      for (int dx = 0; dx < 3; ++dx) s += wv[dr * 3 + dx] * a[dr][j + dx];
    res[j] = (short)f2bf(s);
  }
  *(bf16x8*)(out + pbase + (y0 + row) * 128 + col0) = res;
}

// ---- batched LDS-tiled FFN tail ----
__global__ __launch_bounds__(256) void dw3gelu4_k(const u16* __restrict__ ft,
                                                  const float* __restrict__ w,
                                                  u16* __restrict__ fg) {
  int plane = blockIdx.x >> 3, stripe = blockIdx.x & 7, tid = threadIdx.x;
  int b = plane / 340, c = plane % 340;
  const u16* t1 = ft + ((long)b * 680 + c) * N_PIX;
  const u16* t2 = ft + ((long)b * 680 + 340 + c) * N_PIX;
  u16* g = fg + ((long)b * 340 + c) * N_PIX;
  int y0 = stripe * 16;
  __shared__ __align__(16) u16 ta[18][136];
  __shared__ __align__(16) u16 tb[18][136];
  for (int v = tid; v < 288; v += 256) {
    int r = v >> 4, col = (v & 15) << 3;
    int y = y0 - 1 + r;
    bf16x8 u1, u2;
    #pragma unroll
    for (int i = 0; i < 8; ++i) { u1[i] = 0; u2[i] = 0; }
    if (y >= 0 && y < 128) {
      u1 = *(const bf16x8*)(t1 + y * 128 + col);
      u2 = *(const bf16x8*)(t2 + y * 128 + col);
    }
    *(bf16x8*)&ta[r][col] = u1;
    *(bf16x8*)&tb[r][col] = u2;
  }
  float w1[9], w2[9];
  #pragma unroll
  for (int j = 0; j < 9; ++j) { w1[j] = w[c * 9 + j]; w2[j] = w[(340 + c) * 9 + j]; }
  __syncthreads();
  int row = tid >> 4, col0 = (tid & 15) << 3;
  float a[3][10], bb[3][10];
  #pragma unroll
  for (int dr = 0; dr < 3; ++dr)
    #pragma unroll
    for (int i = 0; i < 10; ++i) {
      int x = col0 - 1 + i;
      bool ok = (x >= 0 && x < 128);
      a[dr][i] = ok ? bf2f(ta[row + dr][x]) : 0.f;
      bb[dr][i] = ok ? bf2f(tb[row + dr][x]) : 0.f;
    }
  bf16x8 res;
  #pragma unroll
  for (int j = 0; j < 8; ++j) {
    float s1 = 0.f, s2 = 0.f;
    #pragma unroll
    for (int dr = 0; dr < 3; ++dr)
      #pragma unroll
      for (int dx = 0; dx < 3; ++dx) {
        s1 += w1[dr * 3 + dx] * a[dr][j + dx];
        s2 += w2[dr * 3 + dx] * bb[dr][j + dx];
      }
    float gl = 0.5f * s1 * (1.f + erff(s1 * 0.70710678118f));
    res[j] = (short)f2bf(gl * s2);
  }
  *(bf16x8*)(g + (y0 + row) * 128 + col0) = res;
}

// ---- merged row L2 norms ----
__global__ __launch_bounds__(256) void rownorm2_k(const u16* __restrict__ q,
                                                  const u16* __restrict__ kv,
                                                  float* __restrict__ qn,
                                                  float* __restrict__ kn) {
  int x = blockIdx.x, b = blockIdx.y, tid = threadIdx.x;
  const u16* src;
  float* dst;
  if (x < 128) { src = q + (long)b * 128 * N_PIX + (long)x * N_PIX; dst = qn + b * 128 + x; }
  else { int r = x - 128; src = kv + (long)b * 256 * N_PIX + (long)r * N_PIX; dst = kn + b * 128 + r; }
  float s = 0.f;
  #pragma unroll
  for (int j = 0; j < 8; ++j) {
    bf16x8 v = *(const bf16x8*)(src + j * 2048 + tid * 8);
    #pragma unroll
    for (int i = 0; i < 8; ++i) { float f = bf2f((u16)v[i]); s += f * f; }
  }
  float t = blockReduceSum256(s);
  if (tid == 0) *dst = sqrtf(t);
}

// ---- attn partials ----
__global__ __launch_bounds__(256) void attn_part_k(const u16* __restrict__ q,
                                                   const u16* __restrict__ kbase,
                                                   long kbstride,
                                                   float* __restrict__ part) {
  int ch = blockIdx.x, h = blockIdx.y, b = blockIdx.z, tid = threadIdx.x;
  int n0 = ch * 256;
  __shared__ __align__(16) u16 qc[16][280];
  __shared__ __align__(16) u16 kc[16][280];
  #pragma unroll
  for (int j = 0; j < 2; ++j) {
    int v = tid + j * 256;
    int r = v >> 5, col = (v & 31) << 3;
    *(bf16x8*)&qc[r][col] = *(const bf16x8*)(q + ((long)b * 128 + h * 16 + r) * N_PIX + n0 + col);
    *(bf16x8*)&kc[r][col] = *(const bf16x8*)(kbase + (long)b * kbstride + (long)(h * 16 + r) * N_PIX + n0 + col);
  }
  __syncthreads();
  int c = tid >> 4, d = tid & 15;
  float acc = 0.f;
  #pragma unroll 4
  for (int nb = 0; nb < 32; ++nb) {
    bf16x8 qv = *(const bf16x8*)&qc[c][nb * 8];
    bf16x8 kv = *(const bf16x8*)&kc[d][nb * 8];
    #pragma unroll
    for (int i = 0; i < 8; ++i) acc += bf2f((u16)qv[i]) * bf2f((u16)kv[i]);
  }
  part[(long)((((b * 8 + h) * 16 + c) * 16 + d)) * 64 + ch] = acc;
}

// ---- reduce partials + cosine scaling ----
__global__ __launch_bounds__(256) void attn_reduce_k(const float* __restrict__ part,
                                                     const float* __restrict__ qn,
                                                     const float* __restrict__ kn,
                                                     const float* __restrict__ temp,
                                                     float* __restrict__ attnm) {
  int idx = blockIdx.x * 256 + threadIdx.x;
  const float* p = part + (long)idx * 64;
  float s = 0.f;
  #pragma unroll
  for (int j = 0; j < 64; ++j) s += p[j];
  int d = idx & 15, c = (idx >> 4) & 15, h = (idx >> 8) & 7, b = idx >> 11;
  float nq = fmaxf(qn[b * 128 + h * 16 + c], 1e-12f);
  float nk = fmaxf(kn[b * 128 + h * 16 + d], 1e-12f);
  attnm[idx] = s / (nq * nk) * temp[h];
}

// ---- top14 threshold + softmax + fold proj into hi/lo Cmb ----
__global__ __launch_bounds__(128) void score_cmb_k(const float* __restrict__ attnm,
                                                   const float* __restrict__ projw,
                                                   const float* __restrict__ attn4p,
                                                   u16* __restrict__ cmbh,
                                                   u16* __restrict__ cmbl) {
  int b = blockIdx.x, tid = threadIdx.x;
  __shared__ float att_s[2048], score_s[2048];
  for (int i = tid; i < 2048; i += 128) att_s[i] = attnm[(long)b * 2048 + i];
  __syncthreads();
  {
    int h = tid >> 4, c = tid & 15;
    float v[16], t[16];
    #pragma unroll
    for (int d = 0; d < 16; ++d) { v[d] = att_s[(h * 16 + c) * 16 + d]; t[d] = v[d]; }
    float thr = 0.f, M = -1e30f;
    for (int it = 0; it < 14; ++it) {
      float m = -1e30f; int mi = 0;
      #pragma unroll
      for (int d = 0; d < 16; ++d) if (t[d] > m) { m = t[d]; mi = d; }
      if (it == 0) M = m;
      thr = m;
      t[mi] = -1e31f;
    }
    float s = 0.f, e[16];
    #pragma unroll
    for (int d = 0; d < 16; ++d) { e[d] = (v[d] >= thr) ? expf(v[d] - M) : 0.f; s += e[d]; }
    float inv = 1.f / s;
    #pragma unroll
    for (int d = 0; d < 16; ++d) score_s[(h * 16 + c) * 16 + d] = e[d] * inv;
  }
  __syncthreads();
  float a4 = attn4p[0];
  int o = tid;
  for (int hd = 0; hd < 128; ++hd) {
    int h = hd >> 4, d = hd & 15;
    float s = 0.f;
    #pragma unroll
    for (int c = 0; c < 16; ++c)
      s += projw[o * 128 + h * 16 + c] * score_s[(h * 16 + c) * 16 + d];
    float v = a4 * s;
    long oi = ((long)b * 128 + o) * 128 + hd;
    u16 hi = f2bf(v);
    cmbh[oi] = hi;
    cmbl[oi] = f2bf(v - bf2f(hi));
  }
}

extern "C" void kernel_launch(void* const* d_in, const int* in_sizes, int n_in,
                              void* d_out, int out_size, void* d_ws, size_t ws_size,
                              hipStream_t stream) {
  (void)in_sizes; (void)n_in; (void)out_size; (void)ws_size;
  const float* vi        = (const float*)d_in[0];
  const float* ir        = (const float*)d_in[1];
  const float* text_code = (const float*)d_in[2];
  const float* se_w1     = (const float*)d_in[3];
  const float* se_w2     = (const float*)d_in[4];
  const float* conv1x1_w = (const float*)d_in[5];
  const float* conv1x1_b = (const float*)d_in[6];
  const float* conv_out_w= (const float*)d_in[7];
  const float* conv_out_b= (const float*)d_in[8];
  const float* text_w1   = (const float*)d_in[9];
  const float* text_b1   = (const float*)d_in[10];
  const float* text_w2   = (const float*)d_in[11];
  const float* text_b2   = (const float*)d_in[12];
  const float* norm1_w   = (const float*)d_in[13];
  const float* norm1_b   = (const float*)d_in[14];
  const float* norm2_w   = (const float*)d_in[15];
  const float* norm2_b   = (const float*)d_in[16];
  const float* norm3_w   = (const float*)d_in[17];
  const float* norm3_b   = (const float*)d_in[18];
  const float* q_w       = (const float*)d_in[19];
  const float* q_dw_w    = (const float*)d_in[20];
  const float* kv_w      = (const float*)d_in[21];
  const float* kv_dw_w   = (const float*)d_in[22];
  const float* temperature = (const float*)d_in[23];
  const float* attn4     = (const float*)d_in[24];
  const float* proj_w    = (const float*)d_in[25];
  const float* ffn_in_w  = (const float*)d_in[26];
  const float* ffn_dw_w  = (const float*)d_in[27];
  const float* ffn_out_w = (const float*)d_in[28];
  float* out0 = (float*)d_out;
  float* out1 = out0 + NP;

  char* W = (char*)d_ws;
  float* sq_f  = (float*)(W + 0);
  int*   idx_i = (int*)(W + 4096);
  int*   sidx_i= (int*)(W + 6144);
  u16*   Mch   = (u16*)(W + 12288);
  u16*   Mcl   = (u16*)(W + 274432);
  float* bcomb = (float*)(W + 536576);
  float* qn_f  = (float*)(W + 538624);
  float* kn_f  = (float*)(W + 540672);
  float* attnm = (float*)(W + 542720);
  u16*   cmbh  = (u16*)(W + 575488);
  u16*   cmbl  = (u16*)(W + 706560);
  float* t1f   = (float*)(W + 834560);
  float* tf_f  = (float*)(W + 842752);
  u16*   W2b   = (u16*)(W + 846848);
  u16*   qwb   = (u16*)(W + 912384);
  u16*   kvwb  = (u16*)(W + 945152);
  u16*   ffnWb = (u16*)(W + (1 << 20));
  u16*   ffnOb = (u16*)(W + (1 << 20) + 174080);
  u16* S    = (u16*)(W + (2 << 20));
  u16* CC   = S;                          // xqT -> Q spatial
  u16* KD   = S + 512L * N_PIX;           // QT -> ATT
  u16* KVD  = S + 1024L * N_PIX;          // concat -> KVD
  u16* CBF  = S + 1024L * N_PIX;
  u16* X3T  = S + 2048L * N_PIX;
  u16* XKVT = S + 2560L * N_PIX;          // xkvT; FT4 overlays later
  u16* FT4  = S + 2560L * N_PIX;
  u16* FG4  = S + 5280L * N_PIX;
  u16* KVT  = (u16*)out0;
  u16* ATT  = KD;

  const long SN = 128L * N_PIX;
  const long SN2 = 256L * N_PIX;

  wconv5_k<<<340, 256, 0, stream>>>(conv_out_w, W2b, 32768, q_w, qwb, 16384,
                                    kv_w, kvwb, 32768, ffn_in_w, ffnWb, 87040,
                                    ffn_out_w, ffnOb, 43520);
  squeeze_k<<<dim3(256, 4), 256, 0, stream>>>(vi, ir, sq_f, CBF);
  se_text1_k<<<dim3(65, 4), 256, 0, stream>>>(sq_f, se_w1, se_w2, idx_i,
                                              text_code, text_w1, text_b1, t1f);
  text2_k<<<dim3(32, 4), 256, 0, stream>>>(t1f, text_w2, text_b2, tf_f);
  rank2_k<<<4, 256, 0, stream>>>(tf_f, sidx_i);
  mcomb_k<<<dim3(128, 4), 128, 0, stream>>>(conv_out_w, conv_out_b, conv1x1_w,
                                            conv1x1_b, idx_i, sidx_i, Mch, Mcl, bcomb);
  // fused dual GEMM + LN1/LN2 (full-o blocks)
  gemm_dual_k<<<dim3(256, 1, 4), 256, 0, stream>>>(
      W2b, conv_out_b, Mch, Mcl, bcomb, CBF, out1, CC, XKVT,
      norm1_w, norm1_b, norm2_w, norm2_b);
  // Q proj / KV proj on normalized transposed activations
  gemm_k<2, 0, 0, 3, 2><<<dim3(256, 1, 4), 256, 0, stream>>>(
      qwb, nullptr, 0, CC, SN, nullptr, 0, KD, SN, 128, 128);
  gemm_k<2, 0, 0, 3, 2><<<dim3(256, 2, 4), 256, 0, stream>>>(
      kvwb, nullptr, 0, XKVT, SN, nullptr, 0, KVT, SN2, 256, 128);
  dw3t2_k<<<12288, 256, 0, stream>>>(KD, q_dw_w, CC, KVT, kv_dw_w, KVD);
  rownorm2_k<<<dim3(256, 4), 256, 0, stream>>>(CC, KVD, qn_f, kn_f);
  float* part = (float*)out0;
  attn_part_k<<<dim3(64, 8, 4), 256, 0, stream>>>(CC, KVD, SN2, part);
  attn_reduce_k<<<32, 256, 0, stream>>>(part, qn_f, kn_f, temperature, attnm);
  score_cmb_k<<<4, 128, 0, stream>>>(attnm, proj_w, attn4, cmbh, cmbl);
  // att = Cmb_b @ V with fused LN3
  att_ln_k<<<dim3(256, 1, 4), 256, 0, stream>>>(
      cmbh, cmbl, KVD + SN, SN2, ATT, X3T, norm3_w, norm3_b);
  // Batched FFN
  gemm_k<2, 0, 0, 3, 2><<<dim3(256, 6, 4), 256, 0, stream>>>(
      ffnWb, nullptr, 0, X3T, SN, nullptr, 0, FT4, 680L * N_PIX, 680, 128);
  dw3gelu4_k<<<10880, 256, 0, stream>>>(FT4, ffn_dw_w, FG4);
  gemm_k<2, 1, 1, 0, 2><<<dim3(256, 1, 4), 256, 0, stream>>>(
      ffnOb, nullptr, 0, FG4, 340L * N_PIX, ATT, SN,
      out0, SN, 128, 340);
}

// Round 23
// 351.733 us; speedup vs baseline: 1.1099x; 1.0140x over previous
//
#include <hip/hip_runtime.h>

typedef unsigned short u16;
typedef __attribute__((ext_vector_type(8))) short bf16x8;
typedef __attribute__((ext_vector_type(4))) float f32x4;

#define N_PIX 16384
static constexpr long NP = 4L * 128 * N_PIX;

__device__ __forceinline__ float bf2f(u16 h) {
  unsigned u = ((unsigned)h) << 16; float f; __builtin_memcpy(&f, &u, 4); return f;
}
__device__ __forceinline__ u16 f2bf(float f) {
  unsigned u; __builtin_memcpy(&u, &f, 4);
  u = (u + 0x7fffu + ((u >> 16) & 1u)) >> 16; return (u16)u;
}

__device__ __forceinline__ float blockReduceSum256(float v) {
  #pragma unroll
  for (int o = 32; o > 0; o >>= 1) v += __shfl_down(v, o, 64);
  __shared__ float sw[4];
  int lane = threadIdx.x & 63, w = threadIdx.x >> 6;
  if (lane == 0) sw[w] = v;
  __syncthreads();
  return (threadIdx.x == 0) ? (sw[0] + sw[1] + sw[2] + sw[3]) : 0.f;
}

// ---- 5 weight tensors f32 -> bf16 ----
__global__ __launch_bounds__(256) void wconv5_k(const float* __restrict__ a0, u16* __restrict__ o0, long n0,
                                                const float* __restrict__ a1, u16* __restrict__ o1, long n1,
                                                const float* __restrict__ a2, u16* __restrict__ o2, long n2,
                                                const float* __restrict__ a3, u16* __restrict__ o3, long n3,
                                                const float* __restrict__ a4, u16* __restrict__ o4, long n4) {
  long i = (long)blockIdx.x * 256 + threadIdx.x;
  if (i < n0) o0[i] = f2bf(a0[i]);
  if (i < n1) o1[i] = f2bf(a1[i]);
  if (i < n2) o2[i] = f2bf(a2[i]);
  if (i < n3) o3[i] = f2bf(a3[i]);
  if (i < n4) o4[i] = f2bf(a4[i]);
}

// ---- squeeze: mean over HW of concat -> [4,256] f32 ; emit bf16 concat ----
__global__ __launch_bounds__(256) void squeeze_k(const float* __restrict__ vi,
                                                 const float* __restrict__ ir,
                                                 float* __restrict__ sq,
                                                 u16* __restrict__ cbf) {
  int c = blockIdx.x, b = blockIdx.y, tid = threadIdx.x;
  const float* src = (c < 128) ? (vi + ((long)b * 128 + c) * N_PIX)
                               : (ir + ((long)b * 128 + (c - 128)) * N_PIX);
  const f32x4* src4 = (const f32x4*)src;
  u16* dst = cbf + ((long)b * 256 + c) * N_PIX;
  float s = 0.f;
  #pragma unroll
  for (int j = 0; j < 8; ++j) {
    f32x4 v0 = src4[j * 512 + tid * 2];
    f32x4 v1 = src4[j * 512 + tid * 2 + 1];
    s += v0.x + v0.y + v0.z + v0.w + v1.x + v1.y + v1.z + v1.w;
    bf16x8 r;
    r[0] = (short)f2bf(v0.x); r[1] = (short)f2bf(v0.y);
    r[2] = (short)f2bf(v0.z); r[3] = (short)f2bf(v0.w);
    r[4] = (short)f2bf(v1.x); r[5] = (short)f2bf(v1.y);
    r[6] = (short)f2bf(v1.z); r[7] = (short)f2bf(v1.w);
    *(bf16x8*)(dst + j * 2048 + tid * 8) = r;
  }
  float t = blockReduceSum256(s);
  if (tid == 0) sq[b * 256 + c] = t * (1.f / 16384.f);
}

// ---- merged: SE MLP + top128 rank (x==64) | text MLP layer1 (x<64) ----
__global__ __launch_bounds__(256) void se_text1_k(const float* __restrict__ sq,
                                                  const float* __restrict__ sew1,
                                                  const float* __restrict__ sew2,
                                                  int* __restrict__ idx,
                                                  const float* __restrict__ tc,
                                                  const float* __restrict__ tw1,
                                                  const float* __restrict__ tb1,
                                                  float* __restrict__ t1f) {
  int b = blockIdx.y, tid = threadIdx.x;
  __shared__ float sm[544];
  if (blockIdx.x == 64) {
    float* s_sq = sm; float* s_h1 = sm + 256; float* s_cw = sm + 288;
    s_sq[tid] = sq[b * 256 + tid];
    __syncthreads();
    if (tid < 32) {
      float s = 0.f;
      for (int c = 0; c < 256; ++c) s += s_sq[c] * sew1[tid * 256 + c];
      s_h1[tid] = fmaxf(s, 0.f);
    }
    __syncthreads();
    {
      float s = 0.f;
      #pragma unroll
      for (int j = 0; j < 32; ++j) s += s_h1[j] * sew2[tid * 32 + j];
      s_cw[tid] = 1.f / (1.f + expf(-s));
    }
    __syncthreads();
    float my = s_cw[tid];
    int rk = 0;
    for (int c = 0; c < 256; ++c) {
      float o = s_cw[c];
      rk += (o > my) || (o == my && c < tid);
    }
    if (rk < 128) idx[b * 128 + rk] = tid;
  } else {
    float* s_tc = sm;
    int j0 = blockIdx.x * 8;
    s_tc[tid] = tc[b * 512 + tid];
    s_tc[tid + 256] = tc[b * 512 + 256 + tid];
    __syncthreads();
    int w = tid >> 6, lane = tid & 63;
    #pragma unroll
    for (int r = 0; r < 2; ++r) {
      int j = j0 + w * 2 + r;
      const float* wr = tw1 + (long)j * 512;
      float s = 0.f;
      #pragma unroll
      for (int k = 0; k < 8; ++k) s += s_tc[lane + k * 64] * wr[lane + k * 64];
      #pragma unroll
      for (int o = 32; o > 0; o >>= 1) s += __shfl_down(s, o, 64);
      if (lane == 0) t1f[b * 512 + j] = fmaxf(s + tb1[j], 0.f);
    }
  }
}

// ---- text MLP layer2 ----
__global__ __launch_bounds__(256) void text2_k(const float* __restrict__ t1f,
                                               const float* __restrict__ tw2,
                                               const float* __restrict__ tb2,
                                               float* __restrict__ tf) {
  int b = blockIdx.y, j0 = blockIdx.x * 8, tid = threadIdx.x;
  __shared__ float s_t1[512];
  s_t1[tid] = t1f[b * 512 + tid];
  s_t1[tid + 256] = t1f[b * 512 + 256 + tid];
  __syncthreads();
  int w = tid >> 6, lane = tid & 63;
  #pragma unroll
  for (int r = 0; r < 2; ++r) {
    int j = j0 + w * 2 + r;
    const float* wr = tw2 + (long)j * 512;
    float s = 0.f;
    #pragma unroll
    for (int k = 0; k < 8; ++k) s += s_t1[lane + k * 64] * wr[lane + k * 64];
    #pragma unroll
    for (int o = 32; o > 0; o >>= 1) s += __shfl_down(s, o, 64);
    if (lane == 0) tf[b * 256 + j] = s + tb2[j];
  }
}

// ---- argsort-rank of tf -> sidx ----
__global__ __launch_bounds__(256) void rank2_k(const float* __restrict__ tf,
                                               int* __restrict__ sidx) {
  int b = blockIdx.x, tid = threadIdx.x;
  __shared__ float s_tf[256];
  s_tf[tid] = tf[b * 256 + tid];
  __syncthreads();
  float my = s_tf[tid];
  int rk = 0;
  for (int c = 0; c < 256; ++c) {
    float o = s_tf[c];
    rk += (o > my) || (o == my && c < tid);
  }
  sidx[b * 256 + rk] = tid;
}

// ---- fold conv1x1+shuffle+conv_out+select into hi/lo bf16 M_b[128,256] ----
__global__ __launch_bounds__(128) void mcomb_k(const float* __restrict__ w2,
                                               const float* __restrict__ w2b,
                                               const float* __restrict__ w1,
                                               const float* __restrict__ w1b,
                                               const int* __restrict__ idx,
                                               const int* __restrict__ sidx,
                                               u16* __restrict__ mch,
                                               u16* __restrict__ mcl,
                                               float* __restrict__ bcomb) {
  int o = blockIdx.x, b = blockIdx.y, tid = threadIdx.x;
  __shared__ float s_w2[256];
  __shared__ int s_sx[256];
  s_w2[tid] = w2[o * 256 + tid];
  s_w2[tid + 128] = w2[o * 256 + tid + 128];
  s_sx[tid] = sidx[b * 256 + tid] & 255;
  s_sx[tid + 128] = sidx[b * 256 + tid + 128] & 255;
  u16* hrow = mch + ((long)b * 128 + o) * 256;
  u16* lrow = mcl + ((long)b * 128 + o) * 256;
  hrow[tid] = 0; hrow[tid + 128] = 0;
  lrow[tid] = 0; lrow[tid + 128] = 0;
  __syncthreads();
  float s = 0.f;
  for (int j = 0; j < 256; ++j) s += s_w2[j] * w1[s_sx[j] * 128 + tid];
  int cc = idx[b * 128 + tid] & 255;
  u16 hi = f2bf(s);
  hrow[cc] = hi;
  lrow[cc] = f2bf(s - bf2f(hi));
  if (tid == 0) {
    float bb = w2b[o];
    for (int j = 0; j < 256; ++j) bb += s_w2[j] * w1b[s_sx[j]];
    bcomb[b * 128 + o] = bb;
  }
}

// ---- fused dual GEMM + LN1/LN2: full 128-o per block; outputs out1 f32 spatial,
//      xqT/xkvT transposed bf16 ALREADY LayerNorm'ed ----
__global__ __launch_bounds__(256) void gemm_dual_k(
    const u16* __restrict__ W2b, const float* __restrict__ b2,
    const u16* __restrict__ Mch, const u16* __restrict__ Mcl,
    const float* __restrict__ bc, const u16* __restrict__ Xb,
    float* __restrict__ out1, u16* __restrict__ xqT, u16* __restrict__ xkvT,
    const float* __restrict__ g1, const float* __restrict__ b1,
    const float* __restrict__ g2, const float* __restrict__ b2n) {
  const int N = N_PIX;
  int n0 = blockIdx.x * 64, bz = blockIdx.z, tid = threadIdx.x;
  __shared__ __align__(16) char smem[36864];
  u16* A1  = (u16*)smem;            // [64][72]
  u16* A2h = (u16*)(smem + 9216);
  u16* A2l = (u16*)(smem + 18432);
  u16* Xs  = (u16*)(smem + 27648);
  __shared__ float gs1[128], bs1[128], gs2[128], bs2[128];
  if (tid < 128) { gs1[tid] = g1[tid]; bs1[tid] = b1[tid]; gs2[tid] = g2[tid]; bs2[tid] = b2n[tid]; }
  f32x4 acc1[2][4], acc2[2][4];
  #pragma unroll
  for (int ot = 0; ot < 2; ++ot)
    #pragma unroll
    for (int i = 0; i < 4; ++i) { acc1[ot][i] = (f32x4){0,0,0,0}; acc2[ot][i] = (f32x4){0,0,0,0}; }
  int wv = tid >> 6, lane = tid & 63;
  int lr = lane & 15, lkq = (lane >> 4) * 8;
  for (int kt = 0; kt < 4; ++kt) {
    int k0 = kt << 6;
    {
      int n = tid & 63;
      const u16* src = Xb + (long)bz * 256 * N + n0 + n;
      #pragma unroll
      for (int cc = 0; cc < 2; ++cc) {
        int kb = ((tid >> 6) << 3) + cc * 32;
        int k = k0 + kb;
        bf16x8 t;
        #pragma unroll
        for (int i = 0; i < 8; ++i) t[i] = (short)src[(long)(k + i) * N];
        *(bf16x8*)&Xs[n * 72 + kb] = t;
      }
    }
    #pragma unroll
    for (int ot = 0; ot < 2; ++ot) {
      {
        int r = tid >> 2, o = ot * 64 + r;
        #pragma unroll
        for (int cc = 0; cc < 2; ++cc) {
          int col = ((tid & 3) << 3) + cc * 32;
          int k = k0 + col;
          *(bf16x8*)&A1[r * 72 + col] = *(const bf16x8*)(W2b + (long)o * 256 + k);
          *(bf16x8*)&A2h[r * 72 + col] = *(const bf16x8*)(Mch + ((long)bz * 128 + o) * 256 + k);
          *(bf16x8*)&A2l[r * 72 + col] = *(const bf16x8*)(Mcl + ((long)bz * 128 + o) * 256 + k);
        }
      }
      __syncthreads();
      #pragma unroll
      for (int kk = 0; kk < 2; ++kk) {
        int lk = kk * 32 + lkq;
        bf16x8 a1 = *(const bf16x8*)&A1[(wv * 16 + lr) * 72 + lk];
        bf16x8 a2h = *(const bf16x8*)&A2h[(wv * 16 + lr) * 72 + lk];
        bf16x8 a2l = *(const bf16x8*)&A2l[(wv * 16 + lr) * 72 + lk];
        #pragma unroll
        for (int nt = 0; nt < 4; ++nt) {
          bf16x8 bfr = *(const bf16x8*)&Xs[(nt * 16 + lr) * 72 + lk];
          acc1[ot][nt] = __builtin_amdgcn_mfma_f32_16x16x32_bf16(a1, bfr, acc1[ot][nt], 0, 0, 0);
          acc2[ot][nt] = __builtin_amdgcn_mfma_f32_16x16x32_bf16(a2h, bfr, acc2[ot][nt], 0, 0, 0);
          acc2[ot][nt] = __builtin_amdgcn_mfma_f32_16x16x32_bf16(a2l, bfr, acc2[ot][nt], 0, 0, 0);
        }
      }
      __syncthreads();
    }
  }
  // ---- pass 1: out1 f32 spatial, per o-tile ----
  float* st1 = (float*)smem;   // [64][68] f32 = 17408B (272B rows, 16B aligned)
  #pragma unroll
  for (int ot = 0; ot < 2; ++ot) {
    #pragma unroll
    for (int nt = 0; nt < 4; ++nt)
      #pragma unroll
      for (int r4 = 0; r4 < 4; ++r4) {
        int o_l = wv * 16 + (lane >> 4) * 4 + r4;
        int n_l = nt * 16 + (lane & 15);
        st1[o_l * 68 + n_l] = acc1[ot][nt][r4] + b2[ot * 64 + o_l];
      }
    __syncthreads();
    {
      int row = tid >> 2, colb = (tid & 3) * 16;
      float* dst = out1 + ((long)bz * 128 + ot * 64 + row) * N + n0 + colb;
      #pragma unroll
      for (int j = 0; j < 4; ++j)
        *(f32x4*)(dst + j * 4) = *(f32x4*)&st1[row * 68 + colb + j * 4];
    }
    __syncthreads();
  }
  // ---- pass 2: qin transposed + LN1 -> xqT  (stride 136 u16 = 272B, 16B aligned) ----
  u16* stq = (u16*)smem;   // [64][136] u16 = 17408B
  #pragma unroll
  for (int ot = 0; ot < 2; ++ot)
    #pragma unroll
    for (int nt = 0; nt < 4; ++nt)
      #pragma unroll
      for (int r4 = 0; r4 < 4; ++r4) {
        int o_a = ot * 64 + wv * 16 + (lane >> 4) * 4 + r4;
        int n_l = nt * 16 + (lane & 15);
        stq[n_l * 136 + o_a] = f2bf(acc2[ot][nt][r4] + bc[bz * 128 + o_a]);
      }
  __syncthreads();
  {
    int n = tid >> 2, c0 = (tid & 3) * 32;
    bf16x8 v[4];
    float sum = 0.f, sq = 0.f;
    #pragma unroll
    for (int j = 0; j < 4; ++j) {
      v[j] = *(const bf16x8*)&stq[n * 136 + c0 + j * 8];
      #pragma unroll
      for (int i = 0; i < 8; ++i) { float f = bf2f((u16)v[j][i]); sum += f; sq += f * f; }
    }
    sum += __shfl_xor(sum, 1, 64); sum += __shfl_xor(sum, 2, 64);
    sq  += __shfl_xor(sq, 1, 64);  sq  += __shfl_xor(sq, 2, 64);
    float mu = sum * (1.f / 128.f);
    float var = sq * (1.f / 128.f) - mu * mu;
    float rs = rsqrtf(fmaxf(var, 0.f) + 1e-5f);
    u16* dst = xqT + ((long)bz * N_PIX + n0 + n) * 128 + c0;
    #pragma unroll
    for (int j = 0; j < 4; ++j) {
      bf16x8 r;
      #pragma unroll
      for (int i = 0; i < 8; ++i) {
        float f = bf2f((u16)v[j][i]);
        r[i] = (short)f2bf((f - mu) * rs * gs1[c0 + j * 8 + i] + bs1[c0 + j * 8 + i]);
      }
      *(bf16x8*)(dst + j * 8) = r;
    }
  }
  __syncthreads();
  // ---- pass 3: img2 transposed + LN2 -> xkvT ----
  #pragma unroll
  for (int ot = 0; ot < 2; ++ot)
    #pragma unroll
    for (int nt = 0; nt < 4; ++nt)
      #pragma unroll
      for (int r4 = 0; r4 < 4; ++r4) {
        int o_a = ot * 64 + wv * 16 + (lane >> 4) * 4 + r4;
        int n_l = nt * 16 + (lane & 15);
        stq[n_l * 136 + o_a] = f2bf(acc1[ot][nt][r4] + b2[o_a]);
      }
  __syncthreads();
  {
    int n = tid >> 2, c0 = (tid & 3) * 32;
    bf16x8 v[4];
    float sum = 0.f, sq = 0.f;
    #pragma unroll
    for (int j = 0; j < 4; ++j) {
      v[j] = *(const bf16x8*)&stq[n * 136 + c0 + j * 8];
      #pragma unroll
      for (int i = 0; i < 8; ++i) { float f = bf2f((u16)v[j][i]); sum += f; sq += f * f; }
    }
    sum += __shfl_xor(sum, 1, 64); sum += __shfl_xor(sum, 2, 64);
    sq  += __shfl_xor(sq, 1, 64);  sq  += __shfl_xor(sq, 2, 64);
    float mu = sum * (1.f / 128.f);
    float var = sq * (1.f / 128.f) - mu * mu;
    float rs = rsqrtf(fmaxf(var, 0.f) + 1e-5f);
    u16* dst = xkvT + ((long)bz * N_PIX + n0 + n) * 128 + c0;
    #pragma unroll
    for (int j = 0; j < 4; ++j) {
      bf16x8 r;
      #pragma unroll
      for (int i = 0; i < 8; ++i) {
        float f = bf2f((u16)v[j][i]);
        r[i] = (short)f2bf((f - mu) * rs * gs2[c0 + j * 8 + i] + bs2[c0 + j * 8 + i]);
      }
      *(bf16x8*)(dst + j * 8) = r;
    }
  }
}

// ---- att GEMM (hi/lo A, spatial V) + fused LN3: outputs ATT bf16 spatial + X3T normalized ----
__global__ __launch_bounds__(256) void att_ln_k(
    const u16* __restrict__ Ah, const u16* __restrict__ Alo,
    const u16* __restrict__ V, long v_bstride,
    u16* __restrict__ att, u16* __restrict__ x3T,
    const float* __restrict__ g3, const float* __restrict__ b3) {
  const int N = N_PIX;
  int n0 = blockIdx.x * 64, bz = blockIdx.z, tid = threadIdx.x;
  int wv = tid >> 6, lane = tid & 63;
  int lr = lane & 15, lkq = (lane >> 4) * 8;
  __shared__ __align__(16) u16 Xs[64][136];
  __shared__ __align__(16) u16 As[64][136];
  __shared__ __align__(16) u16 Al[64][136];
  __shared__ float gs[128], bs[128];
  if (tid < 128) { gs[tid] = g3[tid]; bs[tid] = b3[tid]; }
  f32x4 acc[2][4];
  #pragma unroll
  for (int ot = 0; ot < 2; ++ot)
    #pragma unroll
    for (int i = 0; i < 4; ++i) acc[ot][i] = (f32x4){0.f, 0.f, 0.f, 0.f};
  // stage V (K=128) via k-gather
  {
    int n = tid & 63;
    const u16* src = V + (long)bz * v_bstride + n0 + n;
    #pragma unroll
    for (int cc = 0; cc < 4; ++cc) {
      int kb = ((tid >> 6) << 3) + cc * 32;
      bf16x8 t;
      #pragma unroll
      for (int i = 0; i < 8; ++i) t[i] = (short)src[(long)(kb + i) * N];
      *(bf16x8*)&Xs[n][kb] = t;
    }
  }
  #pragma unroll
  for (int ot = 0; ot < 2; ++ot) {
    {
      int r = tid >> 2, o = ot * 64 + r;
      #pragma unroll
      for (int cc = 0; cc < 4; ++cc) {
        int col = ((tid & 3) << 3) + cc * 32;
        long base = (long)bz * (128L * 128) + (long)o * 128 + col;
        *(bf16x8*)&As[r][col] = *(const bf16x8*)(Ah + base);
        *(bf16x8*)&Al[r][col] = *(const bf16x8*)(Alo + base);
      }
    }
    __syncthreads();
    #pragma unroll
    for (int kk = 0; kk < 4; ++kk) {
      int lk = kk * 32 + lkq;
      bf16x8 afr = *(const bf16x8*)&As[wv * 16 + lr][lk];
      bf16x8 alr = *(const bf16x8*)&Al[wv * 16 + lr][lk];
      #pragma unroll
      for (int nt = 0; nt < 4; ++nt) {
        bf16x8 bfr = *(const bf16x8*)&Xs[nt * 16 + lr][lk];
        acc[ot][nt] = __builtin_amdgcn_mfma_f32_16x16x32_bf16(afr, bfr, acc[ot][nt], 0, 0, 0);
        acc[ot][nt] = __builtin_amdgcn_mfma_f32_16x16x32_bf16(alr, bfr, acc[ot][nt], 0, 0, 0);
      }
    }
    __syncthreads();
  }
  // pass 1: ATT bf16 spatial per o-tile (stage in Xs, stride 72 u16 = 144B, 16B aligned)
  u16* st = &Xs[0][0];
  #pragma unroll
  for (int ot = 0; ot < 2; ++ot) {
    #pragma unroll
    for (int nt = 0; nt < 4; ++nt)
      #pragma unroll
      for (int r4 = 0; r4 < 4; ++r4) {
        int row = wv * 16 + (lane >> 4) * 4 + r4;
        int col = nt * 16 + (lane & 15);
        st[row * 72 + col] = f2bf(acc[ot][nt][r4]);
      }
    __syncthreads();
    #pragma unroll
    for (int it = 0; it < 2; ++it) {
      int row = (tid >> 3) + it * 32;
      int col = (tid & 7) * 8;
      bf16x8 v = *(bf16x8*)&st[row * 72 + col];
      *(bf16x8*)(att + ((long)bz * 128 + ot * 64 + row) * N + n0 + col) = v;
    }
    __syncthreads();
  }
  // pass 2: transposed stage + LN3 -> x3T (stride 136 u16 = 272B, 16B aligned)
  u16* stq = &Xs[0][0];  // reuse as [64][136] = 17408B exactly
  #pragma unroll
  for (int ot = 0; ot < 2; ++ot)
    #pragma unroll
    for (int nt = 0; nt < 4; ++nt)
      #pragma unroll
      for (int r4 = 0; r4 < 4; ++r4) {
        int o_a = ot * 64 + wv * 16 + (lane >> 4) * 4 + r4;
        int n_l = nt * 16 + (lane & 15);
        stq[n_l * 136 + o_a] = f2bf(acc[ot][nt][r4]);
      }
  __syncthreads();
  {
    int n = tid >> 2, c0 = (tid & 3) * 32;
    bf16x8 v[4];
    float sum = 0.f, sq = 0.f;
    #pragma unroll
    for (int j = 0; j < 4; ++j) {
      v[j] = *(const bf16x8*)&stq[n * 136 + c0 + j * 8];
      #pragma unroll
      for (int i = 0; i < 8; ++i) { float f = bf2f((u16)v[j][i]); sum += f; sq += f * f; }
    }
    sum += __shfl_xor(sum, 1, 64); sum += __shfl_xor(sum, 2, 64);
    sq  += __shfl_xor(sq, 1, 64);  sq  += __shfl_xor(sq, 2, 64);
    float mu = sum * (1.f / 128.f);
    float var = sq * (1.f / 128.f) - mu * mu;
    float rs = rsqrtf(fmaxf(var, 0.f) + 1e-5f);
    u16* dst = x3T + ((long)bz * N_PIX + n0 + n) * 128 + c0;
    #pragma unroll
    for (int j = 0; j < 4; ++j) {
      bf16x8 r;
      #pragma unroll
      for (int i = 0; i < 8; ++i) {
        float f = bf2f((u16)v[j][i]);
        r[i] = (short)f2bf((f - mu) * rs * gs[c0 + j * 8 + i] + bs[c0 + j * 8 + i]);
      }
      *(bf16x8*)(dst + j * 8) = r;
    }
  }
}

// ---------------- generic MFMA GEMM, OT o-tiles of 64 rows, coalesced epilogue ----------------
// AMODE: 2=bf16 W. XT: 0=spatial X via LDS k-gather; 3=transposed X via LDS + DIRECT A (K==128)
template<int AMODE, int RESADD, int OUTF, int XT, int OT>
__global__ __launch_bounds__(256) void gemm_k(
    const u16* __restrict__ Ah, const u16* __restrict__ Alo, long a_bstride,
    const u16* __restrict__ X, long x_bstride,
    const u16* __restrict__ res, long res_bstride,
    void* __restrict__ outv, long out_bstride,
    int O, int K) {
  const int N = N_PIX;
  int n0 = blockIdx.x * 64;
  int o0 = blockIdx.y * 64 * OT;
  int bz = blockIdx.z;
  int tid = threadIdx.x;
  int wv = tid >> 6, lane = tid & 63;
  int lr = lane & 15, lkq = (lane >> 4) * 8;
  __shared__ __align__(16) u16 Xs[64][136];
  __shared__ __align__(16) u16 As[(XT == 3) ? 1 : 64][136];
  f32x4 acc[OT][4];
  #pragma unroll
  for (int ot = 0; ot < OT; ++ot)
    #pragma unroll
    for (int i = 0; i < 4; ++i) acc[ot][i] = (f32x4){0.f, 0.f, 0.f, 0.f};

  if (XT == 3) {
    {
      int n = tid >> 2, koff = (tid & 3) << 5;
      const u16* src = X + (long)bz * x_bstride + (long)(n0 + n) * 128 + koff;
      #pragma unroll
      for (int j = 0; j < 4; ++j)
        *(bf16x8*)&Xs[n][koff + j * 8] = *(const bf16x8*)(src + j * 8);
    }
    __syncthreads();
    #pragma unroll
    for (int ot = 0; ot < OT; ++ot) {
      int oc = o0 + ot * 64 + wv * 16 + lr;
      if (oc > O - 1) oc = O - 1;
      const u16* Arow = Ah + (long)oc * 128;
      bf16x8 afr[4];
      #pragma unroll
      for (int kk = 0; kk < 4; ++kk) afr[kk] = *(const bf16x8*)(Arow + kk * 32 + lkq);
      #pragma unroll
      for (int kk = 0; kk < 4; ++kk) {
        int lk = kk * 32 + lkq;
        #pragma unroll
        for (int nt = 0; nt < 4; ++nt) {
          bf16x8 bfr = *(const bf16x8*)&Xs[nt * 16 + lr][lk];
          acc[ot][nt] = __builtin_amdgcn_mfma_f32_16x16x32_bf16(afr[kk], bfr, acc[ot][nt], 0, 0, 0);
        }
      }
    }
    __syncthreads();
  } else {
    int nk = (K + 127) >> 7;
    for (int kt = 0; kt < nk; ++kt) {
      int k0 = kt << 7;
      {
        int n = tid & 63;
        const u16* src = X + (long)bz * x_bstride + n0 + n;
        #pragma unroll
        for (int cc = 0; cc < 4; ++cc) {
          int kb = ((tid >> 6) << 3) + cc * 32;
          int k = k0 + kb;
          bf16x8 t;
          #pragma unroll
          for (int i = 0; i < 8; ++i)
            t[i] = (short)((k + i < K) ? src[(long)(k + i) * N] : (u16)0);
          *(bf16x8*)&Xs[n][kb] = t;
        }
      }
      #pragma unroll
      for (int ot = 0; ot < OT; ++ot) {
        {
          int r = tid >> 2, o = o0 + ot * 64 + r;
          #pragma unroll
          for (int cc = 0; cc < 4; ++cc) {
            int col = ((tid & 3) << 3) + cc * 32;
            int k = k0 + col;
            bf16x8 t;
            if (o < O && k + 8 <= K) {
              t = *(const bf16x8*)(Ah + (long)o * K + k);
            } else {
              #pragma unroll
              for (int i = 0; i < 8; ++i)
                t[i] = (short)((o < O && k + i < K) ? Ah[(long)o * K + k + i] : (u16)0);
            }
            *(bf16x8*)&As[r][col] = t;
          }
        }
        __syncthreads();
        #pragma unroll
        for (int kk = 0; kk < 4; ++kk) {
          int lk = kk * 32 + lkq;
          bf16x8 afr = *(const bf16x8*)&As[wv * 16 + lr][lk];
          #pragma unroll
          for (int nt = 0; nt < 4; ++nt) {
            bf16x8 bfr = *(const bf16x8*)&Xs[nt * 16 + lr][lk];
            acc[ot][nt] = __builtin_amdgcn_mfma_f32_16x16x32_bf16(afr, bfr, acc[ot][nt], 0, 0, 0);
          }
        }
        __syncthreads();
      }
    }
  }

  // ---- coalesced epilogue per o-tile ----
  #pragma unroll
  for (int ot = 0; ot < OT; ++ot) {
    if (ot > 0) __syncthreads();
    if (OUTF == 0) {
      u16* st = &Xs[0][0];   // stride 72 u16 = 144B, 16B aligned
      #pragma unroll
      for (int nt = 0; nt < 4; ++nt)
        #pragma unroll
        for (int r4 = 0; r4 < 4; ++r4) {
          int row = wv * 16 + (lane >> 4) * 4 + r4;
          int col = nt * 16 + (lane & 15);
          st[row * 72 + col] = f2bf(acc[ot][nt][r4]);
        }
      __syncthreads();
      #pragma unroll
      for (int it = 0; it < 2; ++it) {
        int row = (tid >> 3) + it * 32;
        int col = (tid & 7) * 8;
        int o = o0 + ot * 64 + row;
        if (o < O) {
          bf16x8 v = *(bf16x8*)&st[row * 72 + col];
          *(bf16x8*)((u16*)outv + (long)bz * out_bstride + (long)o * N + n0 + col) = v;
        }
      }
    } else {
      float* st = (float*)&Xs[0][0];
      #pragma unroll
      for (int nt = 0; nt < 4; ++nt)
        #pragma unroll
        for (int r4 = 0; r4 < 4; ++r4) {
          int row = wv * 16 + (lane >> 4) * 4 + r4;
          int col = nt * 16 + (lane & 15);
          st[row * 68 + col] = acc[ot][nt][r4];
        }
      __syncthreads();
      {
        int row = tid >> 2, colb = (tid & 3) * 16;
        int o = o0 + ot * 64 + row;
        if (o < O) {
          float* dst = (float*)outv + (long)bz * out_bstride + (long)o * N + n0 + colb;
          bf16x8 rv0, rv1;
          if (RESADD) {
            const u16* rp = res + (long)bz * res_bstride + (long)o * N + n0 + colb;
            rv0 = *(const bf16x8*)rp;
            rv1 = *(const bf16x8*)(rp + 8);
          }
          #pragma unroll
          for (int j = 0; j < 4; ++j) {
            f32x4 v = *(f32x4*)&st[row * 68 + colb + j * 4];
            if (RESADD) {
              #pragma unroll
              for (int i = 0; i < 4; ++i) {
                int idx = j * 4 + i;
                u16 rr = (u16)((idx < 8) ? rv0[idx] : rv1[idx - 8]);
                v[i] += bf2f(rr);
              }
            }
            *(f32x4*)(dst + j * 4) = v;
          }
        }
      }
    }
  }
}

// ---- merged LDS-tiled depthwise 3x3: planes 0..511 = Q, 512..1535 = KV ----
__global__ __launch_bounds__(256) void dw3t2_k(const u16* __restrict__ inQ,
                                               const float* __restrict__ wQ,
                                               u16* __restrict__ outQ,
                                               const u16* __restrict__ inKV,
                                               const float* __restrict__ wKV,
                                               u16* __restrict__ outKV) {
  int gp = blockIdx.x >> 3, stripe = blockIdx.x & 7, tid = threadIdx.x;
  const u16* in; const float* w; u16* out; int c; long pbase;
  if (gp < 512) { in = inQ;  w = wQ;  out = outQ;  c = gp & 127;  pbase = (long)gp * N_PIX; }
  else { int p2 = gp - 512; in = inKV; w = wKV; out = outKV; c = p2 & 255; pbase = (long)p2 * N_PIX; }
  int y0 = stripe * 16;
  __shared__ __align__(16) u16 tile[18][136];
  for (int v = tid; v < 288; v += 256) {
    int r = v >> 4, col = (v & 15) << 3;
    int y = y0 - 1 + r;
    bf16x8 t;
    #pragma unroll
    for (int i = 0; i < 8; ++i) t[i] = 0;
    if (y >= 0 && y < 128) t = *(const bf16x8*)(in + pbase + y * 128 + col);
    *(bf16x8*)&tile[r][col] = t;
  }
  float wv[9];
  #pragma unroll
  for (int j = 0; j < 9; ++j) wv[j] = w[c * 9 + j];
  __syncthreads();
  int row = tid >> 4, col0 = (tid & 15) << 3;
  float a[3][10];
  #pragma unroll
  for (int dr = 0; dr < 3; ++dr)
    #pragma unroll
    for (int i = 0; i < 10; ++i) {
      int x = col0 - 1 + i;
      a[dr][i] = (x >= 0 && x < 128) ? bf2f(tile[row + dr][x]) : 0.f;
    }
  bf16x8 res;
  #pragma unroll
  for (int j = 0; j < 8; ++j) {
    float s = 0.f;
    #pragma unroll
    for (int dr = 0; dr < 3; ++dr)
      #pragma unroll
      for (int dx = 0; dx < 3; ++dx) s += wv[dr * 3 + dx] * a[dr][j + dx];
    res[j] = (short)f2bf(s);
  }
  *(bf16x8*)(out + pbase + (y0 + row) * 128 + col0) = res;
}

// ---- batched LDS-tiled FFN tail ----
__global__ __launch_bounds__(256) void dw3gelu4_k(const u16* __restrict__ ft,
                                                  const float* __restrict__ w,
                                                  u16* __restrict__ fg) {
  int plane = blockIdx.x >> 3, stripe = blockIdx.x & 7, tid = threadIdx.x;
  int b = plane / 340, c = plane % 340;
  const u16* t1 = ft + ((long)b * 680 + c) * N_PIX;
  const u16* t2 = ft + ((long)b * 680 + 340 + c) * N_PIX;
  u16* g = fg + ((long)b * 340 + c) * N_PIX;
  int y0 = stripe * 16;
  __shared__ __align__(16) u16 ta[18][136];
  __shared__ __align__(16) u16 tb[18][136];
  for (int v = tid; v < 288; v += 256) {
    int r = v >> 4, col = (v & 15) << 3;
    int y = y0 - 1 + r;
    bf16x8 u1, u2;
    #pragma unroll
    for (int i = 0; i < 8; ++i) { u1[i] = 0; u2[i] = 0; }
    if (y >= 0 && y < 128) {
      u1 = *(const bf16x8*)(t1 + y * 128 + col);
      u2 = *(const bf16x8*)(t2 + y * 128 + col);
    }
    *(bf16x8*)&ta[r][col] = u1;
    *(bf16x8*)&tb[r][col] = u2;
  }
  float w1[9], w2[9];
  #pragma unroll
  for (int j = 0; j < 9; ++j) { w1[j] = w[c * 9 + j]; w2[j] = w[(340 + c) * 9 + j]; }
  __syncthreads();
  int row = tid >> 4, col0 = (tid & 15) << 3;
  float a[3][10], bb[3][10];
  #pragma unroll
  for (int dr = 0; dr < 3; ++dr)
    #pragma unroll
    for (int i = 0; i < 10; ++i) {
      int x = col0 - 1 + i;
      bool ok = (x >= 0 && x < 128);
      a[dr][i] = ok ? bf2f(ta[row + dr][x]) : 0.f;
      bb[dr][i] = ok ? bf2f(tb[row + dr][x]) : 0.f;
    }
  bf16x8 res;
  #pragma unroll
  for (int j = 0; j < 8; ++j) {
    float s1 = 0.f, s2 = 0.f;
    #pragma unroll
    for (int dr = 0; dr < 3; ++dr)
      #pragma unroll
      for (int dx = 0; dx < 3; ++dx) {
        s1 += w1[dr * 3 + dx] * a[dr][j + dx];
        s2 += w2[dr * 3 + dx] * bb[dr][j + dx];
      }
    float gl = 0.5f * s1 * (1.f + erff(s1 * 0.70710678118f));
    res[j] = (short)f2bf(gl * s2);
  }
  *(bf16x8*)(g + (y0 + row) * 128 + col0) = res;
}

// ---- merged row L2 norms ----
__global__ __launch_bounds__(256) void rownorm2_k(const u16* __restrict__ q,
                                                  const u16* __restrict__ kv,
                                                  float* __restrict__ qn,
                                                  float* __restrict__ kn) {
  int x = blockIdx.x, b = blockIdx.y, tid = threadIdx.x;
  const u16* src;
  float* dst;
  if (x < 128) { src = q + (long)b * 128 * N_PIX + (long)x * N_PIX; dst = qn + b * 128 + x; }
  else { int r = x - 128; src = kv + (long)b * 256 * N_PIX + (long)r * N_PIX; dst = kn + b * 128 + r; }
  float s = 0.f;
  #pragma unroll
  for (int j = 0; j < 8; ++j) {
    bf16x8 v = *(const bf16x8*)(src + j * 2048 + tid * 8);
    #pragma unroll
    for (int i = 0; i < 8; ++i) { float f = bf2f((u16)v[i]); s += f * f; }
  }
  float t = blockReduceSum256(s);
  if (tid == 0) *dst = sqrtf(t);
}

// ---- attn partials ----
__global__ __launch_bounds__(256) void attn_part_k(const u16* __restrict__ q,
                                                   const u16* __restrict__ kbase,
                                                   long kbstride,
                                                   float* __restrict__ part) {
  int ch = blockIdx.x, h = blockIdx.y, b = blockIdx.z, tid = threadIdx.x;
  int n0 = ch * 256;
  __shared__ __align__(16) u16 qc[16][280];
  __shared__ __align__(16) u16 kc[16][280];
  #pragma unroll
  for (int j = 0; j < 2; ++j) {
    int v = tid + j * 256;
    int r = v >> 5, col = (v & 31) << 3;
    *(bf16x8*)&qc[r][col] = *(const bf16x8*)(q + ((long)b * 128 + h * 16 + r) * N_PIX + n0 + col);
    *(bf16x8*)&kc[r][col] = *(const bf16x8*)(kbase + (long)b * kbstride + (long)(h * 16 + r) * N_PIX + n0 + col);
  }
  __syncthreads();
  int c = tid >> 4, d = tid & 15;
  float acc = 0.f;
  #pragma unroll 4
  for (int nb = 0; nb < 32; ++nb) {
    bf16x8 qv = *(const bf16x8*)&qc[c][nb * 8];
    bf16x8 kv = *(const bf16x8*)&kc[d][nb * 8];
    #pragma unroll
    for (int i = 0; i < 8; ++i) acc += bf2f((u16)qv[i]) * bf2f((u16)kv[i]);
  }
  part[(long)((((b * 8 + h) * 16 + c) * 16 + d)) * 64 + ch] = acc;
}

// ---- reduce partials + cosine scaling ----
__global__ __launch_bounds__(256) void attn_reduce_k(const float* __restrict__ part,
                                                     const float* __restrict__ qn,
                                                     const float* __restrict__ kn,
                                                     const float* __restrict__ temp,
                                                     float* __restrict__ attnm) {
  int idx = blockIdx.x * 256 + threadIdx.x;
  const float* p = part + (long)idx * 64;
  float s = 0.f;
  #pragma unroll
  for (int j = 0; j < 64; ++j) s += p[j];
  int d = idx & 15, c = (idx >> 4) & 15, h = (idx >> 8) & 7, b = idx >> 11;
  float nq = fmaxf(qn[b * 128 + h * 16 + c], 1e-12f);
  float nk = fmaxf(kn[b * 128 + h * 16 + d], 1e-12f);
  attnm[idx] = s / (nq * nk) * temp[h];
}

// ---- top14 threshold + softmax + fold proj into hi/lo Cmb ----
__global__ __launch_bounds__(128) void score_cmb_k(const float* __restrict__ attnm,
                                                   const float* __restrict__ projw,
                                                   const float* __restrict__ attn4p,
                                                   u16* __restrict__ cmbh,
                                                   u16* __restrict__ cmbl) {
  int b = blockIdx.x, tid = threadIdx.x;
  __shared__ float att_s[2048], score_s[2048];
  for (int i = tid; i < 2048; i += 128) att_s[i] = attnm[(long)b * 2048 + i];
  __syncthreads();
  {
    int h = tid >> 4, c = tid & 15;
    float v[16], t[16];
    #pragma unroll
    for (int d = 0; d < 16; ++d) { v[d] = att_s[(h * 16 + c) * 16 + d]; t[d] = v[d]; }
    float thr = 0.f, M = -1e30f;
    for (int it = 0; it < 14; ++it) {
      float m = -1e30f; int mi = 0;
      #pragma unroll
      for (int d = 0; d < 16; ++d) if (t[d] > m) { m = t[d]; mi = d; }
      if (it == 0) M = m;
      thr = m;
      t[mi] = -1e31f;
    }
    float s = 0.f, e[16];
    #pragma unroll
    for (int d = 0; d < 16; ++d) { e[d] = (v[d] >= thr) ? expf(v[d] - M) : 0.f; s += e[d]; }
    float inv = 1.f / s;
    #pragma unroll
    for (int d = 0; d < 16; ++d) score_s[(h * 16 + c) * 16 + d] = e[d] * inv;
  }
  __syncthreads();
  float a4 = attn4p[0];
  int o = tid;
  for (int hd = 0; hd < 128; ++hd) {
    int h = hd >> 4, d = hd & 15;
    float s = 0.f;
    #pragma unroll
    for (int c = 0; c < 16; ++c)
      s += projw[o * 128 + h * 16 + c] * score_s[(h * 16 + c) * 16 + d];
    float v = a4 * s;
    long oi = ((long)b * 128 + o) * 128 + hd;
    u16 hi = f2bf(v);
    cmbh[oi] = hi;
    cmbl[oi] = f2bf(v - bf2f(hi));
  }
}

extern "C" void kernel_launch(void* const* d_in, const int* in_sizes, int n_in,
                              void* d_out, int out_size, void* d_ws, size_t ws_size,
                              hipStream_t stream) {
  (void)in_sizes; (void)n_in; (void)out_size; (void)ws_size;
  const float* vi        = (const float*)d_in[0];
  const float* ir        = (const float*)d_in[1];
  const float* text_code = (const float*)d_in[2];
  const float* se_w1     = (const float*)d_in[3];
  const float* se_w2     = (const float*)d_in[4];
  const float* conv1x1_w = (const float*)d_in[5];
  const float* conv1x1_b = (const float*)d_in[6];
  const float* conv_out_w= (const float*)d_in[7];
  const float* conv_out_b= (const float*)d_in[8];
  const float* text_w1   = (const float*)d_in[9];
  const float* text_b1   = (const float*)d_in[10];
  const float* text_w2   = (const float*)d_in[11];
  const float* text_b2   = (const float*)d_in[12];
  const float* norm1_w   = (const float*)d_in[13];
  const float* norm1_b   = (const float*)d_in[14];
  const float* norm2_w   = (const float*)d_in[15];
  const float* norm2_b   = (const float*)d_in[16];
  const float* norm3_w   = (const float*)d_in[17];
  const float* norm3_b   = (const float*)d_in[18];
  const float* q_w       = (const float*)d_in[19];
  const float* q_dw_w    = (const float*)d_in[20];
  const float* kv_w      = (const float*)d_in[21];
  const float* kv_dw_w   = (const float*)d_in[22];
  const float* temperature = (const float*)d_in[23];
  const float* attn4     = (const float*)d_in[24];
  const float* proj_w    = (const float*)d_in[25];
  const float* ffn_in_w  = (const float*)d_in[26];
  const float* ffn_dw_w  = (const float*)d_in[27];
  const float* ffn_out_w = (const float*)d_in[28];
  float* out0 = (float*)d_out;
  float* out1 = out0 + NP;

  char* W = (char*)d_ws;
  float* sq_f  = (float*)(W + 0);
  int*   idx_i = (int*)(W + 4096);
  int*   sidx_i= (int*)(W + 6144);
  u16*   Mch   = (u16*)(W + 12288);
  u16*   Mcl   = (u16*)(W + 274432);
  float* bcomb = (float*)(W + 536576);
  float* qn_f  = (float*)(W + 538624);
  float* kn_f  = (float*)(W + 540672);
  float* attnm = (float*)(W + 542720);
  u16*   cmbh  = (u16*)(W + 575488);
  u16*   cmbl  = (u16*)(W + 706560);
  float* t1f   = (float*)(W + 834560);
  float* tf_f  = (float*)(W + 842752);
  u16*   W2b   = (u16*)(W + 846848);
  u16*   qwb   = (u16*)(W + 912384);
  u16*   kvwb  = (u16*)(W + 945152);
  u16*   ffnWb = (u16*)(W + (1 << 20));
  u16*   ffnOb = (u16*)(W + (1 << 20) + 174080);
  u16* S    = (u16*)(W + (2 << 20));
  u16* CC   = S;                          // xqT -> Q spatial
  u16* KD   = S + 512L * N_PIX;           // QT -> ATT
  u16* KVD  = S + 1024L * N_PIX;          // concat -> KVD
  u16* CBF  = S + 1024L * N_PIX;
  u16* X3T  = S + 2048L * N_PIX;
  u16* XKVT = S + 2560L * N_PIX;          // xkvT; FT4 overlays later
  u16* FT4  = S + 2560L * N_PIX;
  u16* FG4  = S + 5280L * N_PIX;
  u16* KVT  = (u16*)out0;
  u16* ATT  = KD;

  const long SN = 128L * N_PIX;
  const long SN2 = 256L * N_PIX;

  wconv5_k<<<340, 256, 0, stream>>>(conv_out_w, W2b, 32768, q_w, qwb, 16384,
                                    kv_w, kvwb, 32768, ffn_in_w, ffnWb, 87040,
                                    ffn_out_w, ffnOb, 43520);
  squeeze_k<<<dim3(256, 4), 256, 0, stream>>>(vi, ir, sq_f, CBF);
  se_text1_k<<<dim3(65, 4), 256, 0, stream>>>(sq_f, se_w1, se_w2, idx_i,
                                              text_code, text_w1, text_b1, t1f);
  text2_k<<<dim3(32, 4), 256, 0, stream>>>(t1f, text_w2, text_b2, tf_f);
  rank2_k<<<4, 256, 0, stream>>>(tf_f, sidx_i);
  mcomb_k<<<dim3(128, 4), 128, 0, stream>>>(conv_out_w, conv_out_b, conv1x1_w,
                                            conv1x1_b, idx_i, sidx_i, Mch, Mcl, bcomb);
  // fused dual GEMM + LN1/LN2 (full-o blocks)
  gemm_dual_k<<<dim3(256, 1, 4), 256, 0, stream>>>(
      W2b, conv_out_b, Mch, Mcl, bcomb, CBF, out1, CC, XKVT,
      norm1_w, norm1_b, norm2_w, norm2_b);
  // Q proj / KV proj on normalized transposed activations
  gemm_k<2, 0, 0, 3, 2><<<dim3(256, 1, 4), 256, 0, stream>>>(
      qwb, nullptr, 0, CC, SN, nullptr, 0, KD, SN, 128, 128);
  gemm_k<2, 0, 0, 3, 2><<<dim3(256, 2, 4), 256, 0, stream>>>(
      kvwb, nullptr, 0, XKVT, SN, nullptr, 0, KVT, SN2, 256, 128);
  dw3t2_k<<<12288, 256, 0, stream>>>(KD, q_dw_w, CC, KVT, kv_dw_w, KVD);
  rownorm2_k<<<dim3(256, 4), 256, 0, stream>>>(CC, KVD, qn_f, kn_f);
  float* part = (float*)out0;
  attn_part_k<<<dim3(64, 8, 4), 256, 0, stream>>>(CC, KVD, SN2, part);
  attn_reduce_k<<<32, 256, 0, stream>>>(part, qn_f, kn_f, temperature, attnm);
  score_cmb_k<<<4, 128, 0, stream>>>(attnm, proj_w, attn4, cmbh, cmbl);
  // att = Cmb_b @ V with fused LN3
  att_ln_k<<<dim3(256, 1, 4), 256, 0, stream>>>(
      cmbh, cmbl, KVD + SN, SN2, ATT, X3T, norm3_w, norm3_b);
  // Batched FFN
  gemm_k<2, 0, 0, 3, 2><<<dim3(256, 6, 4), 256, 0, stream>>>(
      ffnWb, nullptr, 0, X3T, SN, nullptr, 0, FT4, 680L * N_PIX, 680, 128);
  dw3gelu4_k<<<10880, 256, 0, stream>>>(FT4, ffn_dw_w, FG4);
  gemm_k<2, 1, 1, 0, 2><<<dim3(256, 1, 4), 256, 0, stream>>>(
      ffnOb, nullptr, 0, FG4, 340L * N_PIX, ATT, SN,
      out0, SN, 128, 340);
}